// Round 7
// baseline (880.449 us; speedup 1.0000x reference)
//
#include <hip/hip_runtime.h>

// ======================================================================
// VQ-VAE forward, all-MFMA. B=32, CIN=3, IMG=128, D=256, K=512.
// NHWC bf16 activations. Occupancy-first layout: every heavy kernel
// launches >=1024 blocks (>=4/CU). mres fused (3x3 -> LDS -> 1x1 + res)
// at M=32/block; mconv2 N-split; mdeconv1 channel-split + N-split +
// parity-split (grid 4096, 27 KB LDS). Weights frag-ordered
// Wf[khkw][cch][n][32]. MFMA 16x16x32 bf16: A[m=lane&15][k=quad*8+j],
// B[n][k], D col=lane&15, row=quad*4+reg (HW-verified mappings).
// ======================================================================

typedef __attribute__((ext_vector_type(8))) short bf16x8;
typedef __attribute__((ext_vector_type(4))) float f32x4;
#define MFMA_B16(a, b, c) __builtin_amdgcn_mfma_f32_16x16x32_bf16(a, b, c, 0, 0, 0)

__device__ inline unsigned short f2b(float f) {
    unsigned int u = __float_as_uint(f);
    unsigned int r = u + 0x7fffu + ((u >> 16) & 1u);
    return (unsigned short)(r >> 16);
}
__device__ inline float b2f(unsigned short u) {
    return __uint_as_float(((unsigned int)u) << 16);
}

// ======================================================================
// prep_all: [0,18432) frag-permute 10 conv weights; rest misc.
// ======================================================================
struct PermfArgs {
    const float* src[10];
    int kw[10];
    int so[10], si[10], sh[10], sw[10];
    int cum[11];
};

__global__ void prep_all_k(PermfArgs a, unsigned short* __restrict__ dst,
                           const float* __restrict__ dt2_w, unsigned short* __restrict__ wg,
                           const float* __restrict__ embed, unsigned short* __restrict__ embF,
                           const float* __restrict__ e_w1, unsigned short* __restrict__ wgc,
                           float* __restrict__ nrm, float* __restrict__ lacc)
{
    int blkid = blockIdx.x;
    int tid = threadIdx.x;
    if (blkid < 18432) {
        int gid = blkid * 256 + tid;
        if (gid >= a.cum[10]) return;
        int seg = 0;
        while (seg < 9 && gid >= a.cum[seg + 1]) ++seg;
        int l = gid - a.cum[seg];
        int q = l & 31;
        int n = (l >> 5) & 255;
        int rest = l >> 13;
        int cch = rest & 7;
        int khkw = rest >> 3;
        int kh = khkw / a.kw[seg], kw = khkw % a.kw[seg];
        int ci = cch * 32 + q;
        dst[gid] = f2b(a.src[seg][n * a.so[seg] + ci * a.si[seg] + kh * a.sh[seg] + kw * a.sw[seg]]);
        return;
    }
    int blk = blkid - 18432;
    if (blk < 48) {                       // deconv2 weights, N=48: n=(kh*4+kw)*3+oc
        int idx = blk * 256 + tid;
        int q = idx & 31;
        int n = (idx >> 5) % 48;
        int cch = idx / (48 * 32);
        int ci = cch * 32 + q;
        int oc = n % 3, khkw = n / 3;
        int kh = khkw >> 2, kw = khkw & 3;
        wg[idx] = f2b(dt2_w[ci * 48 + oc * 16 + kh * 4 + kw]);
    } else if (blk < 560) {               // codebook frag: dst[(cch*512+n)*32+q]
        int idx = (blk - 48) * 256 + tid;
        int q = idx & 31;
        int n = (idx >> 5) & 511;
        int cch = idx >> 14;
        embF[idx] = f2b(embed[n * 256 + cch * 32 + q]);
    } else if (blk < 624) {               // conv1 im2col weights, K=48 pad 64
        int idx = (blk - 560) * 256 + tid;
        int q = idx & 31;
        int n = (idx >> 5) & 255;
        int kt = idx >> 13;
        int k = kt * 32 + q;
        float v = 0.f;
        if (k < 48) {
            int ci = k >> 4, kh = (k >> 2) & 3, kwv = k & 3;
            v = e_w1[n * 48 + ci * 16 + kh * 4 + kwv];
        }
        wgc[idx] = f2b(v);
    } else if (blk < 752) {               // codebook row norms, 4 rows/block
        int row = (blk - 624) * 4 + (tid >> 6);
        int lane = tid & 63;
        float s = 0.f;
        #pragma unroll
        for (int c = 0; c < 256; c += 64) {
            float v = embed[row * 256 + c + lane];
            s += v * v;
        }
        #pragma unroll
        for (int off = 1; off < 64; off <<= 1) s += __shfl_xor(s, off);
        if (lane == 0) nrm[row] = s;
    } else {
        if (tid == 0) lacc[0] = 0.f;
    }
}

// ======================================================================
// conv1m: MFMA im2col conv1. x NCHW fp32 -> NHWC bf16 (B,64,64,256),
// k4 s2 p1, ReLU. grid = B*64. K=48 pad 64.
// ======================================================================
__global__ void __launch_bounds__(256, 4)
conv1m_k(const float* __restrict__ x, const unsigned short* __restrict__ wgc,
         unsigned short* __restrict__ out)
{
    int bh = blockIdx.x;
    int b = bh >> 6, oh = bh & 63;
    int tid = threadIdx.x;
    int lane = tid & 63, wv = tid >> 6;
    int m = lane & 15, quad = lane >> 4;
    __shared__ float xrow[3][4][130];
    __shared__ __align__(16) unsigned short imc[64 * 72];
    for (int s = tid; s < 1560; s += 256) {
        int col = s % 130;
        int t = s / 130;
        int r = t & 3;
        int c = t >> 2;
        int ih = 2 * oh - 1 + r, iw = col - 1;
        float v = 0.f;
        if ((unsigned)ih < 128u && (unsigned)iw < 128u)
            v = x[(((b * 3 + c) << 7) + ih) * 128 + iw];
        xrow[c][r][col] = v;
    }
    __syncthreads();
    for (int s = tid; s < 4096; s += 256) {
        int px = s >> 6, k = s & 63;
        float v = 0.f;
        if (k < 48) {
            int ci = k >> 4, kh = (k >> 2) & 3, kw = k & 3;
            v = xrow[ci][kh][2 * px + kw];
        }
        imc[px * 72 + k] = f2b(v);
    }
    __syncthreads();
    f32x4 acc[16];
    f32x4 z = {0.f, 0.f, 0.f, 0.f};
    #pragma unroll
    for (int i = 0; i < 16; ++i) acc[i] = z;
    bf16x8 a0 = *(const bf16x8*)&imc[((wv << 4) + m) * 72 + (quad << 3)];
    bf16x8 a1 = *(const bf16x8*)&imc[((wv << 4) + m) * 72 + 32 + (quad << 3)];
    #pragma unroll
    for (int nt = 0; nt < 16; ++nt) {
        bf16x8 b0 = *(const bf16x8*)&wgc[(nt * 16 + m) * 32 + (quad << 3)];
        bf16x8 b1 = *(const bf16x8*)&wgc[(256 + nt * 16 + m) * 32 + (quad << 3)];
        acc[nt] = MFMA_B16(a0, b0, acc[nt]);
        acc[nt] = MFMA_B16(a1, b1, acc[nt]);
    }
    #pragma unroll
    for (int nt = 0; nt < 16; ++nt)
        #pragma unroll
        for (int r = 0; r < 4; ++r) {
            int px = (wv << 4) + quad * 4 + r;
            out[(((bh << 6) + px) << 8) + nt * 16 + (lane & 15)] = f2b(fmaxf(acc[nt][r], 0.f));
        }
}

// ======================================================================
// mconv2: k4 s2 p1, (B,64,64,256)->(B,32,32,256), ReLU. M=64, N=128.
// grid = B*16*2 = 1024. Channel-split staging, parity-split cols.
// ======================================================================
__global__ void __launch_bounds__(256, 4)
mconv2_k(const unsigned short* __restrict__ in, const unsigned short* __restrict__ wf,
         unsigned short* __restrict__ out)
{
    int blk = blockIdx.x;
    int bb = blk >> 5;
    int rem = blk & 31;
    int j = rem >> 1;
    int nh = rem & 1;
    int lane = threadIdx.x & 63;
    int n0 = (nh << 7) + ((threadIdx.x >> 6) << 5);   // wave covers 32 cols
    int m = lane & 15, quad = lane >> 4;
    __shared__ __align__(16) unsigned short win[2 * 66 * 132];  // 34.8 KB
    f32x4 acc[2][2][2];   // [row][mt][nt]
    f32x4 z = {0.f, 0.f, 0.f, 0.f};
    #pragma unroll
    for (int a = 0; a < 2; ++a)
        #pragma unroll
        for (int i = 0; i < 2; ++i)
            #pragma unroll
            for (int t = 0; t < 2; ++t) acc[a][i][t] = z;

    for (int c0 = 0; c0 < 256; c0 += 128) {
        for (int kh = 0; kh < 4; ++kh) {
            __syncthreads();
            for (int s = threadIdx.x; s < 2 * 66 * 16; s += 256) {
                int c16 = s & 15;
                int t2 = s >> 4;
                int col = t2 % 66;
                int rr = t2 / 66;
                int ih = 4 * j - 1 + kh + 2 * rr, iw = col - 1;
                int4 v = make_int4(0, 0, 0, 0);
                if ((unsigned)ih < 64u && (unsigned)iw < 64u)
                    v = *(const int4*)&in[((((bb << 6) + ih) << 6) + iw) * 256 + c0 + (c16 << 3)];
                int cs = (col >> 1) + (col & 1) * 33;
                *(int4*)&win[(rr * 66 + cs) * 132 + (c16 << 3)] = v;
            }
            __syncthreads();
            #pragma unroll
            for (int kw = 0; kw < 4; ++kw) {
                int csoff = (kw >> 1) + (kw & 1) * 33;
                #pragma unroll
                for (int cch = 0; cch < 4; ++cch) {
                    bf16x8 a00 = *(const bf16x8*)&win[(m + csoff) * 132 + (cch << 5) + (quad << 3)];
                    bf16x8 a01 = *(const bf16x8*)&win[(m + 16 + csoff) * 132 + (cch << 5) + (quad << 3)];
                    bf16x8 a10 = *(const bf16x8*)&win[(66 + m + csoff) * 132 + (cch << 5) + (quad << 3)];
                    bf16x8 a11 = *(const bf16x8*)&win[(66 + m + 16 + csoff) * 132 + (cch << 5) + (quad << 3)];
                    int cg = (c0 >> 5) + cch;
                    int wbase = ((((kh << 2) + kw) * 8 + cg) * 256 + n0 + m) * 32 + (quad << 3);
                    bf16x8 b0 = *(const bf16x8*)&wf[wbase];
                    bf16x8 b1 = *(const bf16x8*)&wf[wbase + 16 * 32];
                    acc[0][0][0] = MFMA_B16(a00, b0, acc[0][0][0]);
                    acc[0][0][1] = MFMA_B16(a00, b1, acc[0][0][1]);
                    acc[0][1][0] = MFMA_B16(a01, b0, acc[0][1][0]);
                    acc[0][1][1] = MFMA_B16(a01, b1, acc[0][1][1]);
                    acc[1][0][0] = MFMA_B16(a10, b0, acc[1][0][0]);
                    acc[1][0][1] = MFMA_B16(a10, b1, acc[1][0][1]);
                    acc[1][1][0] = MFMA_B16(a11, b0, acc[1][1][0]);
                    acc[1][1][1] = MFMA_B16(a11, b1, acc[1][1][1]);
                }
            }
        }
    }
    #pragma unroll
    for (int row = 0; row < 2; ++row) {
        int oh = 2 * j + row;
        #pragma unroll
        for (int mt = 0; mt < 2; ++mt)
            #pragma unroll
            for (int nt = 0; nt < 2; ++nt)
                #pragma unroll
                for (int r = 0; r < 4; ++r) {
                    int px = mt * 16 + quad * 4 + r;
                    int col = n0 + nt * 16 + m;
                    out[((((bb << 5) + oh) << 5) + px) * 256 + col] = f2b(fmaxf(acc[row][mt][nt][r], 0.f));
                }
    }
}

// ======================================================================
// mres: fused residual block: out = 1x1(relu(3x3(in))) + res. M=32
// (one output row per block). grid = B*32 = 1024. LDS 27 KB.
// ======================================================================
__global__ void __launch_bounds__(256, 4)
mres_k(const unsigned short* __restrict__ in, const unsigned short* __restrict__ wf3,
       const unsigned short* __restrict__ wf1, const unsigned short* __restrict__ res,
       unsigned short* __restrict__ outb, float* __restrict__ outf, int f32out)
{
    int blk = blockIdx.x;            // bb*32 + oh
    int bb = blk >> 5, oh = blk & 31;
    int lane = threadIdx.x & 63;
    int n0 = (threadIdx.x >> 6) << 6;
    int m = lane & 15, quad = lane >> 4;
    __shared__ __align__(16) unsigned short win[3 * 34 * 132];  // 26.9 KB; aliased as mid[32*264]
    f32x4 acc[2][4];
    f32x4 z = {0.f, 0.f, 0.f, 0.f};
    #pragma unroll
    for (int i = 0; i < 2; ++i)
        #pragma unroll
        for (int t = 0; t < 4; ++t) acc[i][t] = z;

    // ---- phase 1: 3x3 conv ----
    for (int c0 = 0; c0 < 256; c0 += 128) {
        __syncthreads();
        for (int s = threadIdx.x; s < 3 * 34 * 16; s += 256) {
            int c16 = s & 15;
            int t2 = s >> 4;
            int col = t2 % 34;
            int rr = t2 / 34;
            int ih = oh - 1 + rr, iw = col - 1;
            int4 v = make_int4(0, 0, 0, 0);
            if ((unsigned)ih < 32u && (unsigned)iw < 32u)
                v = *(const int4*)&in[((((bb << 5) + ih) << 5) + iw) * 256 + c0 + (c16 << 3)];
            *(int4*)&win[(rr * 34 + col) * 132 + (c16 << 3)] = v;
        }
        __syncthreads();
        for (int kh = 0; kh < 3; ++kh) {
            #pragma unroll
            for (int kw = 0; kw < 3; ++kw) {
                #pragma unroll
                for (int cch = 0; cch < 4; ++cch) {
                    const unsigned short* ba = &win[(kh * 34 + m + kw) * 132 + (cch << 5) + (quad << 3)];
                    bf16x8 a0 = *(const bf16x8*)ba;
                    bf16x8 a1 = *(const bf16x8*)(ba + 16 * 132);
                    int cg = (c0 >> 5) + cch;
                    int wbase = (((kh * 3 + kw) * 8 + cg) * 256 + n0 + m) * 32 + (quad << 3);
                    bf16x8 b0 = *(const bf16x8*)&wf3[wbase];
                    bf16x8 b1 = *(const bf16x8*)&wf3[wbase + 16 * 32];
                    bf16x8 b2 = *(const bf16x8*)&wf3[wbase + 32 * 32];
                    bf16x8 b3 = *(const bf16x8*)&wf3[wbase + 48 * 32];
                    acc[0][0] = MFMA_B16(a0, b0, acc[0][0]);
                    acc[0][1] = MFMA_B16(a0, b1, acc[0][1]);
                    acc[0][2] = MFMA_B16(a0, b2, acc[0][2]);
                    acc[0][3] = MFMA_B16(a0, b3, acc[0][3]);
                    acc[1][0] = MFMA_B16(a1, b0, acc[1][0]);
                    acc[1][1] = MFMA_B16(a1, b1, acc[1][1]);
                    acc[1][2] = MFMA_B16(a1, b2, acc[1][2]);
                    acc[1][3] = MFMA_B16(a1, b3, acc[1][3]);
                }
            }
        }
    }

    // ---- relu -> LDS (mid aliases win: 32*264 = 8448 <= 13464 shorts) ----
    __syncthreads();
    unsigned short* mid = win;
    #pragma unroll
    for (int mt = 0; mt < 2; ++mt)
        #pragma unroll
        for (int nt = 0; nt < 4; ++nt)
            #pragma unroll
            for (int r = 0; r < 4; ++r) {
                int px = mt * 16 + quad * 4 + r;
                int col = n0 + nt * 16 + m;
                mid[px * 264 + col] = f2b(fmaxf(acc[mt][nt][r], 0.f));
            }
    __syncthreads();

    // ---- phase 2: 1x1 + residual ----
    f32x4 acc2[2][4];
    #pragma unroll
    for (int i = 0; i < 2; ++i)
        #pragma unroll
        for (int t = 0; t < 4; ++t) acc2[i][t] = z;
    #pragma unroll
    for (int cch = 0; cch < 8; ++cch) {
        bf16x8 a0 = *(const bf16x8*)&mid[m * 264 + (cch << 5) + (quad << 3)];
        bf16x8 a1 = *(const bf16x8*)&mid[(m + 16) * 264 + (cch << 5) + (quad << 3)];
        int wbase = (cch * 256 + n0 + m) * 32 + (quad << 3);
        bf16x8 b0 = *(const bf16x8*)&wf1[wbase];
        bf16x8 b1 = *(const bf16x8*)&wf1[wbase + 16 * 32];
        bf16x8 b2 = *(const bf16x8*)&wf1[wbase + 32 * 32];
        bf16x8 b3 = *(const bf16x8*)&wf1[wbase + 48 * 32];
        acc2[0][0] = MFMA_B16(a0, b0, acc2[0][0]);
        acc2[0][1] = MFMA_B16(a0, b1, acc2[0][1]);
        acc2[0][2] = MFMA_B16(a0, b2, acc2[0][2]);
        acc2[0][3] = MFMA_B16(a0, b3, acc2[0][3]);
        acc2[1][0] = MFMA_B16(a1, b0, acc2[1][0]);
        acc2[1][1] = MFMA_B16(a1, b1, acc2[1][1]);
        acc2[1][2] = MFMA_B16(a1, b2, acc2[1][2]);
        acc2[1][3] = MFMA_B16(a1, b3, acc2[1][3]);
    }
    int rowbase = blk << 13;   // 32 px * 256
    #pragma unroll
    for (int mt = 0; mt < 2; ++mt)
        #pragma unroll
        for (int nt = 0; nt < 4; ++nt)
            #pragma unroll
            for (int r = 0; r < 4; ++r) {
                int px = mt * 16 + quad * 4 + r;
                int col = n0 + nt * 16 + m;
                int idx = rowbase + (px << 8) + col;
                float v = acc2[mt][nt][r] + b2f(res[idx]);
                outb[idx] = f2b(v);
                if (f32out) outf[idx] = v;
            }
}

// ======================================================================
// mdeconv1: ConvTranspose2d(256->256,k4,s2,p1)+bias+ReLU. Two same-parity
// oy rows per block; channel-split staging (27 KB); N-split (128 cols) and
// ox-parity-split across blocks. grid = B*32*2*2 = 4096.
// ======================================================================
__global__ void __launch_bounds__(256, 4)
mdeconv1_k(const unsigned short* __restrict__ in, const unsigned short* __restrict__ wf,
           const float* __restrict__ bias, unsigned short* __restrict__ out)
{
    int blk = blockIdx.x;
    int bb = blk >> 7;
    int rem = blk & 127;
    int par = rem & 1;                  // ox parity
    int nh = (rem >> 1) & 1;            // n half
    int r2 = rem >> 2;
    int pp = r2 >> 4;                   // oy parity group
    int i = r2 & 15;
    int oy_a = pp + 4 * i;              // rows oy_a, oy_a+2
    int p = (oy_a + 1) & 1;
    int r0a = (oy_a + 1 - p) >> 1;
    int rbase = r0a - 1;                // input rows rbase..rbase+2
    int lane = threadIdx.x & 63;
    int n0 = (nh << 7) + ((threadIdx.x >> 6) << 5);
    int m = lane & 15, quad = lane >> 4;
    __shared__ __align__(16) unsigned short win[3 * 34 * 132];   // 26.9 KB

    f32x4 acc[2][2][2];   // [row][mt][nt]
    f32x4 z = {0.f, 0.f, 0.f, 0.f};
    #pragma unroll
    for (int a = 0; a < 2; ++a)
        #pragma unroll
        for (int i2 = 0; i2 < 2; ++i2)
            #pragma unroll
            for (int t = 0; t < 2; ++t) acc[a][i2][t] = z;

    for (int c0 = 0; c0 < 256; c0 += 128) {
        __syncthreads();
        for (int s = threadIdx.x; s < 3 * 34 * 16; s += 256) {
            int c16 = s & 15;
            int t2 = s >> 4;
            int col = t2 % 34;
            int rr = t2 / 34;
            int ih = rbase + rr, iw = col - 1;
            int4 v = make_int4(0, 0, 0, 0);
            if ((unsigned)ih < 32u && (unsigned)iw < 32u)
                v = *(const int4*)&in[((((bb << 5) + ih) << 5) + iw) * 256 + c0 + (c16 << 3)];
            *(int4*)&win[(rr * 34 + col) * 132 + (c16 << 3)] = v;
        }
        __syncthreads();
        #pragma unroll
        for (int t = 0; t < 2; ++t) {
            int kh = p + 2 * t;
            #pragma unroll
            for (int u = 0; u < 2; ++u) {
                int kw = (1 - par) + 2 * u;
                int ixoff = par - u + 1;
                #pragma unroll
                for (int cch = 0; cch < 4; ++cch) {
                    const unsigned short* baA = &win[((1 - t) * 34 + m + ixoff) * 132 + (cch << 5) + (quad << 3)];
                    const unsigned short* baB = &win[((2 - t) * 34 + m + ixoff) * 132 + (cch << 5) + (quad << 3)];
                    bf16x8 a00 = *(const bf16x8*)baA;
                    bf16x8 a01 = *(const bf16x8*)(baA + 16 * 132);
                    bf16x8 a10 = *(const bf16x8*)baB;
                    bf16x8 a11 = *(const bf16x8*)(baB + 16 * 132);
                    int cg = (c0 >> 5) + cch;
                    int wbase = ((((kh << 2) + kw) * 8 + cg) * 256 + n0 + m) * 32 + (quad << 3);
                    bf16x8 b0 = *(const bf16x8*)&wf[wbase];
                    bf16x8 b1 = *(const bf16x8*)&wf[wbase + 16 * 32];
                    acc[0][0][0] = MFMA_B16(a00, b0, acc[0][0][0]);
                    acc[0][0][1] = MFMA_B16(a00, b1, acc[0][0][1]);
                    acc[0][1][0] = MFMA_B16(a01, b0, acc[0][1][0]);
                    acc[0][1][1] = MFMA_B16(a01, b1, acc[0][1][1]);
                    acc[1][0][0] = MFMA_B16(a10, b0, acc[1][0][0]);
                    acc[1][0][1] = MFMA_B16(a10, b1, acc[1][0][1]);
                    acc[1][1][0] = MFMA_B16(a11, b0, acc[1][1][0]);
                    acc[1][1][1] = MFMA_B16(a11, b1, acc[1][1][1]);
                }
            }
        }
    }
    #pragma unroll
    for (int row = 0; row < 2; ++row) {
        int oy = oy_a + 2 * row;
        #pragma unroll
        for (int mt = 0; mt < 2; ++mt)
            #pragma unroll
            for (int nt = 0; nt < 2; ++nt) {
                int col = n0 + nt * 16 + m;
                float bs = bias[col];
                #pragma unroll
                for (int r = 0; r < 4; ++r) {
                    int ox = 2 * (mt * 16 + quad * 4 + r) + par;
                    float v = fmaxf(acc[row][mt][nt][r] + bs, 0.f);
                    out[((((bb << 6) + oy) << 6) + ox) * 256 + col] = f2b(v);
                }
            }
    }
}

// ======================================================================
// vqm: MFMA VQ + exact fp32 gather/loss. grid = B*32.
// ======================================================================
__global__ void __launch_bounds__(256, 2)
vqm_k(const unsigned short* __restrict__ zeb, const float* __restrict__ zef,
      const unsigned short* __restrict__ embF, const float* __restrict__ embed,
      const float* __restrict__ nrm, unsigned short* __restrict__ zq,
      float* __restrict__ lacc)
{
    int bh = blockIdx.x;
    int tid = threadIdx.x;
    int lane = tid & 63;
    int wv = tid >> 6;
    int m = lane & 15, quad = lane >> 4;
    __shared__ __align__(16) unsigned short win[32 * 264];
    __shared__ float bvv[4][32];
    __shared__ int   bii[4][32];
    __shared__ int   bidx[32];
    int rowbase = bh << 13;
    for (int s = tid; s < 32 * 32; s += 256) {
        int c8 = s & 31, px = s >> 5;
        *(int4*)&win[px * 264 + (c8 << 3)] = *(const int4*)&zeb[rowbase + (px << 8) + (c8 << 3)];
    }
    __syncthreads();

    f32x4 acc[2][8];
    f32x4 z = {0.f, 0.f, 0.f, 0.f};
    #pragma unroll
    for (int i = 0; i < 2; ++i)
        #pragma unroll
        for (int j = 0; j < 8; ++j) acc[i][j] = z;

    #pragma unroll
    for (int cch = 0; cch < 8; ++cch) {
        bf16x8 a0 = *(const bf16x8*)&win[m * 264 + (cch << 5) + (quad << 3)];
        bf16x8 a1 = *(const bf16x8*)&win[(m + 16) * 264 + (cch << 5) + (quad << 3)];
        #pragma unroll
        for (int nt = 0; nt < 8; ++nt) {
            bf16x8 b = *(const bf16x8*)&embF[((cch << 9) + (wv << 7) + (nt << 4) + m) * 32 + (quad << 3)];
            acc[0][nt] = MFMA_B16(a0, b, acc[0][nt]);
            acc[1][nt] = MFMA_B16(a1, b, acc[1][nt]);
        }
    }

    float nv[8];
    #pragma unroll
    for (int nt = 0; nt < 8; ++nt) nv[nt] = nrm[(wv << 7) + (nt << 4) + m];

    #pragma unroll
    for (int mt = 0; mt < 2; ++mt)
        #pragma unroll
        for (int r = 0; r < 4; ++r) {
            float bv = 1e30f;
            int bi = 0x7fffffff;
            #pragma unroll
            for (int nt = 0; nt < 8; ++nt) {
                float d = nv[nt] - 2.f * acc[mt][nt][r];
                int n = (wv << 7) + (nt << 4) + m;
                if (d < bv || (d == bv && n < bi)) { bv = d; bi = n; }
            }
            #pragma unroll
            for (int off = 1; off < 16; off <<= 1) {
                float ov = __shfl_xor(bv, off);
                int oi = __shfl_xor(bi, off);
                if (ov < bv || (ov == bv && oi < bi)) { bv = ov; bi = oi; }
            }
            if (m == 0) {
                int px = mt * 16 + quad * 4 + r;
                bvv[wv][px] = bv;
                bii[wv][px] = bi;
            }
        }
    __syncthreads();
    if (tid < 32) {
        float bv = bvv[0][tid];
        int bi = bii[0][tid];
        #pragma unroll
        for (int w2 = 1; w2 < 4; ++w2) {
            float ov = bvv[w2][tid];
            int oi = bii[w2][tid];
            if (ov < bv || (ov == bv && oi < bi)) { bv = ov; bi = oi; }
        }
        bidx[tid] = bi;
    }
    __syncthreads();

    float lsum = 0.f;
    #pragma unroll
    for (int j = 0; j < 8; ++j) {
        int px = (wv << 3) + j;
        int bi = bidx[px];
        int pix = (bh << 5) + px;
        const float4 e = *(const float4*)&embed[bi * 256 + (lane << 2)];
        const float4 zv = *(const float4*)&zef[(pix << 8) + (lane << 2)];
        ushort4 eq;
        eq.x = f2b(e.x); eq.y = f2b(e.y); eq.z = f2b(e.z); eq.w = f2b(e.w);
        *(ushort4*)&zq[(pix << 8) + (lane << 2)] = eq;
        float dx = zv.x - e.x, dy = zv.y - e.y, dz = zv.z - e.z, dw = zv.w - e.w;
        lsum += dx * dx + dy * dy + dz * dz + dw * dw;
    }
    #pragma unroll
    for (int off = 1; off < 64; off <<= 1) lsum += __shfl_xor(lsum, off);
    if (lane == 0) atomicAdd(lacc, lsum);
}

// ======================================================================
// mdec2a: deconv2 pass 1 — Y[B*64*64, 48] = X[.,256] x Wg[256,48]
// ======================================================================
__global__ void __launch_bounds__(256, 4)
mdec2a_k(const unsigned short* __restrict__ in, const unsigned short* __restrict__ wg,
         float* __restrict__ Y)
{
    int tid = threadIdx.x;
    int lane = tid & 63;
    int wv = tid >> 6;
    int m = lane & 15, quad = lane >> 4;
    __shared__ __align__(16) unsigned short win[64 * 264];
    int pxbase = blockIdx.x << 6;
    for (int s = tid; s < 64 * 32; s += 256) {
        int c8 = s & 31, px = s >> 5;
        *(int4*)&win[px * 264 + (c8 << 3)] = *(const int4*)&in[((pxbase + px) << 8) + (c8 << 3)];
    }
    __syncthreads();
    f32x4 acc[3];
    f32x4 z = {0.f, 0.f, 0.f, 0.f};
    acc[0] = z; acc[1] = z; acc[2] = z;
    #pragma unroll
    for (int cch = 0; cch < 8; ++cch) {
        bf16x8 a = *(const bf16x8*)&win[((wv << 4) + m) * 264 + (cch << 5) + (quad << 3)];
        #pragma unroll
        for (int nt = 0; nt < 3; ++nt) {
            bf16x8 b = *(const bf16x8*)&wg[(cch * 48 + nt * 16 + m) * 32 + (quad << 3)];
            acc[nt] = MFMA_B16(a, b, acc[nt]);
        }
    }
    #pragma unroll
    for (int nt = 0; nt < 3; ++nt)
        #pragma unroll
        for (int r = 0; r < 4; ++r) {
            int px = pxbase + (wv << 4) + quad * 4 + r;
            Y[px * 48 + nt * 16 + m] = acc[nt][r];
        }
}

// ======================================================================
// dec2b: deconv2 pass 2 — gather taps, +bias, sigmoid, NCHW out + losses.
// ======================================================================
__global__ void dec2b_k(const float* __restrict__ Y, const float* __restrict__ bias,
                        const float* __restrict__ lacc, float* __restrict__ out)
{
    if (blockIdx.x == 0 && threadIdx.x == 0) {
        float mloss = lacc[0] * (1.0f / 32768.0f);
        out[1572864] = mloss;
        out[1572865] = mloss;
    }
    int idx = blockIdx.x * 256 + threadIdx.x;
    int b = idx >> 14;
    int rem = idx & 16383;
    int oy = rem >> 7;
    int ox = rem & 127;
    int p = (oy + 1) & 1;
    int q = (ox + 1) & 1;
    float acc0 = bias[0], acc1 = bias[1], acc2 = bias[2];
    #pragma unroll
    for (int t = 0; t < 2; ++t) {
        int kh = p + 2 * t;
        int ih = (oy + 1 - kh) >> 1;
        if ((unsigned)ih >= 64u) continue;
        #pragma unroll
        for (int u = 0; u < 2; ++u) {
            int kw = q + 2 * u;
            int iw = (ox + 1 - kw) >> 1;
            if ((unsigned)iw >= 64u) continue;
            int base = ((((b << 6) + ih) << 6) + iw) * 48 + ((kh << 2) + kw) * 3;
            acc0 += Y[base];
            acc1 += Y[base + 1];
            acc2 += Y[base + 2];
        }
    }
    int obase = (b * 3 << 14) + (oy << 7) + ox;
    out[obase]           = 1.f / (1.f + expf(-acc0));
    out[obase + 16384]   = 1.f / (1.f + expf(-acc1));
    out[obase + 32768]   = 1.f / (1.f + expf(-acc2));
}

// ======================================================================
extern "C" void kernel_launch(void* const* d_in, const int* in_sizes, int n_in,
                              void* d_out, int out_size, void* d_ws, size_t ws_size,
                              hipStream_t stream)
{
    (void)in_sizes; (void)n_in; (void)out_size; (void)ws_size;
    const float* x      = (const float*)d_in[0];
    const float* embed  = (const float*)d_in[1];
    const float* e_w1   = (const float*)d_in[2];
    const float* e_w2   = (const float*)d_in[3];
    const float* e_r1a  = (const float*)d_in[4];
    const float* e_r1b  = (const float*)d_in[5];
    const float* e_r2a  = (const float*)d_in[6];
    const float* e_r2b  = (const float*)d_in[7];
    const float* d_r1a  = (const float*)d_in[8];
    const float* d_r1b  = (const float*)d_in[9];
    const float* d_r2a  = (const float*)d_in[10];
    const float* d_r2b  = (const float*)d_in[11];
    const float* dt1_w  = (const float*)d_in[12];
    const float* dt1_b  = (const float*)d_in[13];
    const float* dt2_w  = (const float*)d_in[14];
    const float* dt2_b  = (const float*)d_in[15];
    float* outp = (float*)d_out;

    // ---- workspace layout ----
    char* base = (char*)d_ws;
    size_t off = 0;
    auto alloc = [&](size_t bytes) { char* p = base + off; off += (bytes + 255) & ~size_t(255); return p; };
    unsigned short* A0b = (unsigned short*)alloc(67108864);  // (B,64,64,256) bf16
    float*          A1f = (float*)alloc(33554432);           // ze fp32; later Y
    unsigned short* L0  = (unsigned short*)alloc(16777216);
    unsigned short* L1  = (unsigned short*)alloc(16777216);
    unsigned short* Wf  = (unsigned short*)alloc(9437184);   // 10 frag-ordered weights
    unsigned short* Wg  = (unsigned short*)alloc(24576);     // deconv2 frag weights
    unsigned short* EmbF = (unsigned short*)alloc(262144);   // codebook frag bf16
    unsigned short* WgC = (unsigned short*)alloc(32768);     // conv1 frag weights
    float* Nrm  = (float*)alloc(2048);
    float* Lacc = (float*)alloc(64);
    float* Y = A1f;   // alias: ze dead after vqm_k

    unsigned short* Wf_ew2  = Wf;
    unsigned short* Wf_er1a = Wf + 1048576;
    unsigned short* Wf_er1b = Wf + 1638400;
    unsigned short* Wf_er2a = Wf + 1703936;
    unsigned short* Wf_er2b = Wf + 2293760;
    unsigned short* Wf_dr1a = Wf + 2359296;
    unsigned short* Wf_dr1b = Wf + 2949120;
    unsigned short* Wf_dr2a = Wf + 3014656;
    unsigned short* Wf_dr2b = Wf + 3604480;
    unsigned short* Wf_dt1  = Wf + 3670016;

    PermfArgs pa;
    const float* srcs[10] = {e_w2, e_r1a, e_r1b, e_r2a, e_r2b, d_r1a, d_r1b, d_r2a, d_r2b, dt1_w};
    int kws[10] = {4, 3, 1, 3, 1, 3, 1, 3, 1, 4};
    int sos[10] = {4096, 2304, 256, 2304, 256, 2304, 256, 2304, 256, 16};
    int sis[10] = {16, 9, 1, 9, 1, 9, 1, 9, 1, 4096};
    int shs[10] = {4, 3, 0, 3, 0, 3, 0, 3, 0, 4};
    int sws[10] = {1, 1, 0, 1, 0, 1, 0, 1, 0, 1};
    int cums[11] = {0, 1048576, 1638400, 1703936, 2293760, 2359296,
                    2949120, 3014656, 3604480, 3670016, 4718592};
    for (int k = 0; k < 10; ++k) {
        pa.src[k] = srcs[k]; pa.kw[k] = kws[k]; pa.so[k] = sos[k];
        pa.si[k] = sis[k]; pa.sh[k] = shs[k]; pa.sw[k] = sws[k];
        pa.cum[k] = cums[k];
    }
    pa.cum[10] = cums[10];

    prep_all_k<<<19185, 256, 0, stream>>>(pa, Wf, dt2_w, Wg, embed, EmbF, e_w1, WgC, Nrm, Lacc);

    // ---- encoder ----
    conv1m_k<<<32 * 64, 256, 0, stream>>>(x, WgC, A0b);
    mconv2_k<<<32 * 32, 256, 0, stream>>>(A0b, Wf_ew2, L1);                    // h
    mres_k<<<32 * 32, 256, 0, stream>>>(L1, Wf_er1a, Wf_er1b, L1, L0, nullptr, 0);   // r1 -> L0
    mres_k<<<32 * 32, 256, 0, stream>>>(L0, Wf_er2a, Wf_er2b, L0, L1, A1f, 1);       // ze -> L1 (bf16) + A1f (fp32)

    // ---- VQ ----
    vqm_k<<<32 * 32, 256, 0, stream>>>(L1, A1f, EmbF, embed, Nrm, L1, Lacc);   // zq -> L1

    // ---- decoder ----
    mres_k<<<32 * 32, 256, 0, stream>>>(L1, Wf_dr1a, Wf_dr1b, L1, L0, nullptr, 0);   // d1 -> L0
    mres_k<<<32 * 32, 256, 0, stream>>>(L0, Wf_dr2a, Wf_dr2b, L0, L1, nullptr, 0);   // d2 -> L1
    mdeconv1_k<<<32 * 128, 256, 0, stream>>>(L1, Wf_dt1, dt1_b, A0b);
    mdec2a_k<<<2048, 256, 0, stream>>>(A0b, Wg, Y);
    dec2b_k<<<2048, 256, 0, stream>>>(Y, dt2_b, Lacc, outp);
}

// Round 8
// 861.534 us; speedup vs baseline: 1.0220x; 1.0220x over previous
//
#include <hip/hip_runtime.h>

// ======================================================================
// VQ-VAE forward, all-MFMA. B=32, CIN=3, IMG=128, D=256, K=512.
// NHWC bf16 activations. mres fused (3x3 -> LDS -> 1x1 + res) at M=32;
// mconv2 M=64/N=128; mdeconv1: both ox-parities per block (1024
// MFMAs/wave, R5 structure) + channel-split staging (26.3 KB LDS ->
// 4 blocks/CU), grid 1024. Weights frag-ordered Wf[khkw][cch][n][32].
// MFMA 16x16x32 bf16: A[m=lane&15][k=quad*8+j], B[n][k], D col=lane&15,
// row=quad*4+reg (HW-verified mappings).
// ======================================================================

typedef __attribute__((ext_vector_type(8))) short bf16x8;
typedef __attribute__((ext_vector_type(4))) float f32x4;
#define MFMA_B16(a, b, c) __builtin_amdgcn_mfma_f32_16x16x32_bf16(a, b, c, 0, 0, 0)

__device__ inline unsigned short f2b(float f) {
    unsigned int u = __float_as_uint(f);
    unsigned int r = u + 0x7fffu + ((u >> 16) & 1u);
    return (unsigned short)(r >> 16);
}
__device__ inline float b2f(unsigned short u) {
    return __uint_as_float(((unsigned int)u) << 16);
}

// ======================================================================
// prep_all: [0,18432) frag-permute 10 conv weights; rest misc.
// ======================================================================
struct PermfArgs {
    const float* src[10];
    int kw[10];
    int so[10], si[10], sh[10], sw[10];
    int cum[11];
};

__global__ void prep_all_k(PermfArgs a, unsigned short* __restrict__ dst,
                           const float* __restrict__ dt2_w, unsigned short* __restrict__ wg,
                           const float* __restrict__ embed, unsigned short* __restrict__ embF,
                           const float* __restrict__ e_w1, unsigned short* __restrict__ wgc,
                           float* __restrict__ nrm, float* __restrict__ lacc)
{
    int blkid = blockIdx.x;
    int tid = threadIdx.x;
    if (blkid < 18432) {
        int gid = blkid * 256 + tid;
        if (gid >= a.cum[10]) return;
        int seg = 0;
        while (seg < 9 && gid >= a.cum[seg + 1]) ++seg;
        int l = gid - a.cum[seg];
        int q = l & 31;
        int n = (l >> 5) & 255;
        int rest = l >> 13;
        int cch = rest & 7;
        int khkw = rest >> 3;
        int kh = khkw / a.kw[seg], kw = khkw % a.kw[seg];
        int ci = cch * 32 + q;
        dst[gid] = f2b(a.src[seg][n * a.so[seg] + ci * a.si[seg] + kh * a.sh[seg] + kw * a.sw[seg]]);
        return;
    }
    int blk = blkid - 18432;
    if (blk < 48) {                       // deconv2 weights, N=48: n=(kh*4+kw)*3+oc
        int idx = blk * 256 + tid;
        int q = idx & 31;
        int n = (idx >> 5) % 48;
        int cch = idx / (48 * 32);
        int ci = cch * 32 + q;
        int oc = n % 3, khkw = n / 3;
        int kh = khkw >> 2, kw = khkw & 3;
        wg[idx] = f2b(dt2_w[ci * 48 + oc * 16 + kh * 4 + kw]);
    } else if (blk < 560) {               // codebook frag: dst[(cch*512+n)*32+q]
        int idx = (blk - 48) * 256 + tid;
        int q = idx & 31;
        int n = (idx >> 5) & 511;
        int cch = idx >> 14;
        embF[idx] = f2b(embed[n * 256 + cch * 32 + q]);
    } else if (blk < 624) {               // conv1 im2col weights, K=48 pad 64
        int idx = (blk - 560) * 256 + tid;
        int q = idx & 31;
        int n = (idx >> 5) & 255;
        int kt = idx >> 13;
        int k = kt * 32 + q;
        float v = 0.f;
        if (k < 48) {
            int ci = k >> 4, kh = (k >> 2) & 3, kwv = k & 3;
            v = e_w1[n * 48 + ci * 16 + kh * 4 + kwv];
        }
        wgc[idx] = f2b(v);
    } else if (blk < 752) {               // codebook row norms, 4 rows/block
        int row = (blk - 624) * 4 + (tid >> 6);
        int lane = tid & 63;
        float s = 0.f;
        #pragma unroll
        for (int c = 0; c < 256; c += 64) {
            float v = embed[row * 256 + c + lane];
            s += v * v;
        }
        #pragma unroll
        for (int off = 1; off < 64; off <<= 1) s += __shfl_xor(s, off);
        if (lane == 0) nrm[row] = s;
    } else {
        if (tid == 0) lacc[0] = 0.f;
    }
}

// ======================================================================
// conv1m: MFMA im2col conv1. x NCHW fp32 -> NHWC bf16 (B,64,64,256),
// k4 s2 p1, ReLU. grid = B*64. K=48 pad 64.
// ======================================================================
__global__ void __launch_bounds__(256, 4)
conv1m_k(const float* __restrict__ x, const unsigned short* __restrict__ wgc,
         unsigned short* __restrict__ out)
{
    int bh = blockIdx.x;
    int b = bh >> 6, oh = bh & 63;
    int tid = threadIdx.x;
    int lane = tid & 63, wv = tid >> 6;
    int m = lane & 15, quad = lane >> 4;
    __shared__ float xrow[3][4][130];
    __shared__ __align__(16) unsigned short imc[64 * 72];
    for (int s = tid; s < 1560; s += 256) {
        int col = s % 130;
        int t = s / 130;
        int r = t & 3;
        int c = t >> 2;
        int ih = 2 * oh - 1 + r, iw = col - 1;
        float v = 0.f;
        if ((unsigned)ih < 128u && (unsigned)iw < 128u)
            v = x[(((b * 3 + c) << 7) + ih) * 128 + iw];
        xrow[c][r][col] = v;
    }
    __syncthreads();
    for (int s = tid; s < 4096; s += 256) {
        int px = s >> 6, k = s & 63;
        float v = 0.f;
        if (k < 48) {
            int ci = k >> 4, kh = (k >> 2) & 3, kw = k & 3;
            v = xrow[ci][kh][2 * px + kw];
        }
        imc[px * 72 + k] = f2b(v);
    }
    __syncthreads();
    f32x4 acc[16];
    f32x4 z = {0.f, 0.f, 0.f, 0.f};
    #pragma unroll
    for (int i = 0; i < 16; ++i) acc[i] = z;
    bf16x8 a0 = *(const bf16x8*)&imc[((wv << 4) + m) * 72 + (quad << 3)];
    bf16x8 a1 = *(const bf16x8*)&imc[((wv << 4) + m) * 72 + 32 + (quad << 3)];
    #pragma unroll
    for (int nt = 0; nt < 16; ++nt) {
        bf16x8 b0 = *(const bf16x8*)&wgc[(nt * 16 + m) * 32 + (quad << 3)];
        bf16x8 b1 = *(const bf16x8*)&wgc[(256 + nt * 16 + m) * 32 + (quad << 3)];
        acc[nt] = MFMA_B16(a0, b0, acc[nt]);
        acc[nt] = MFMA_B16(a1, b1, acc[nt]);
    }
    #pragma unroll
    for (int nt = 0; nt < 16; ++nt)
        #pragma unroll
        for (int r = 0; r < 4; ++r) {
            int px = (wv << 4) + quad * 4 + r;
            out[(((bh << 6) + px) << 8) + nt * 16 + (lane & 15)] = f2b(fmaxf(acc[nt][r], 0.f));
        }
}

// ======================================================================
// mconv2: k4 s2 p1, (B,64,64,256)->(B,32,32,256), ReLU. M=64, N=128.
// grid = B*16*2 = 1024. Channel-split staging, parity-split cols.
// ======================================================================
__global__ void __launch_bounds__(256, 4)
mconv2_k(const unsigned short* __restrict__ in, const unsigned short* __restrict__ wf,
         unsigned short* __restrict__ out)
{
    int blk = blockIdx.x;
    int bb = blk >> 5;
    int rem = blk & 31;
    int j = rem >> 1;
    int nh = rem & 1;
    int lane = threadIdx.x & 63;
    int n0 = (nh << 7) + ((threadIdx.x >> 6) << 5);   // wave covers 32 cols
    int m = lane & 15, quad = lane >> 4;
    __shared__ __align__(16) unsigned short win[2 * 66 * 132];  // 34.8 KB
    f32x4 acc[2][2][2];   // [row][mt][nt]
    f32x4 z = {0.f, 0.f, 0.f, 0.f};
    #pragma unroll
    for (int a = 0; a < 2; ++a)
        #pragma unroll
        for (int i = 0; i < 2; ++i)
            #pragma unroll
            for (int t = 0; t < 2; ++t) acc[a][i][t] = z;

    for (int c0 = 0; c0 < 256; c0 += 128) {
        for (int kh = 0; kh < 4; ++kh) {
            __syncthreads();
            for (int s = threadIdx.x; s < 2 * 66 * 16; s += 256) {
                int c16 = s & 15;
                int t2 = s >> 4;
                int col = t2 % 66;
                int rr = t2 / 66;
                int ih = 4 * j - 1 + kh + 2 * rr, iw = col - 1;
                int4 v = make_int4(0, 0, 0, 0);
                if ((unsigned)ih < 64u && (unsigned)iw < 64u)
                    v = *(const int4*)&in[((((bb << 6) + ih) << 6) + iw) * 256 + c0 + (c16 << 3)];
                int cs = (col >> 1) + (col & 1) * 33;
                *(int4*)&win[(rr * 66 + cs) * 132 + (c16 << 3)] = v;
            }
            __syncthreads();
            #pragma unroll
            for (int kw = 0; kw < 4; ++kw) {
                int csoff = (kw >> 1) + (kw & 1) * 33;
                #pragma unroll
                for (int cch = 0; cch < 4; ++cch) {
                    bf16x8 a00 = *(const bf16x8*)&win[(m + csoff) * 132 + (cch << 5) + (quad << 3)];
                    bf16x8 a01 = *(const bf16x8*)&win[(m + 16 + csoff) * 132 + (cch << 5) + (quad << 3)];
                    bf16x8 a10 = *(const bf16x8*)&win[(66 + m + csoff) * 132 + (cch << 5) + (quad << 3)];
                    bf16x8 a11 = *(const bf16x8*)&win[(66 + m + 16 + csoff) * 132 + (cch << 5) + (quad << 3)];
                    int cg = (c0 >> 5) + cch;
                    int wbase = ((((kh << 2) + kw) * 8 + cg) * 256 + n0 + m) * 32 + (quad << 3);
                    bf16x8 b0 = *(const bf16x8*)&wf[wbase];
                    bf16x8 b1 = *(const bf16x8*)&wf[wbase + 16 * 32];
                    acc[0][0][0] = MFMA_B16(a00, b0, acc[0][0][0]);
                    acc[0][0][1] = MFMA_B16(a00, b1, acc[0][0][1]);
                    acc[0][1][0] = MFMA_B16(a01, b0, acc[0][1][0]);
                    acc[0][1][1] = MFMA_B16(a01, b1, acc[0][1][1]);
                    acc[1][0][0] = MFMA_B16(a10, b0, acc[1][0][0]);
                    acc[1][0][1] = MFMA_B16(a10, b1, acc[1][0][1]);
                    acc[1][1][0] = MFMA_B16(a11, b0, acc[1][1][0]);
                    acc[1][1][1] = MFMA_B16(a11, b1, acc[1][1][1]);
                }
            }
        }
    }
    #pragma unroll
    for (int row = 0; row < 2; ++row) {
        int oh = 2 * j + row;
        #pragma unroll
        for (int mt = 0; mt < 2; ++mt)
            #pragma unroll
            for (int nt = 0; nt < 2; ++nt)
                #pragma unroll
                for (int r = 0; r < 4; ++r) {
                    int px = mt * 16 + quad * 4 + r;
                    int col = n0 + nt * 16 + m;
                    out[((((bb << 5) + oh) << 5) + px) * 256 + col] = f2b(fmaxf(acc[row][mt][nt][r], 0.f));
                }
    }
}

// ======================================================================
// mres: fused residual block: out = 1x1(relu(3x3(in))) + res. M=32
// (one output row per block). grid = B*32 = 1024. LDS 27 KB.
// ======================================================================
__global__ void __launch_bounds__(256, 4)
mres_k(const unsigned short* __restrict__ in, const unsigned short* __restrict__ wf3,
       const unsigned short* __restrict__ wf1, const unsigned short* __restrict__ res,
       unsigned short* __restrict__ outb, float* __restrict__ outf, int f32out)
{
    int blk = blockIdx.x;            // bb*32 + oh
    int bb = blk >> 5, oh = blk & 31;
    int lane = threadIdx.x & 63;
    int n0 = (threadIdx.x >> 6) << 6;
    int m = lane & 15, quad = lane >> 4;
    __shared__ __align__(16) unsigned short win[3 * 34 * 132];  // 26.9 KB; aliased as mid[32*264]
    f32x4 acc[2][4];
    f32x4 z = {0.f, 0.f, 0.f, 0.f};
    #pragma unroll
    for (int i = 0; i < 2; ++i)
        #pragma unroll
        for (int t = 0; t < 4; ++t) acc[i][t] = z;

    // ---- phase 1: 3x3 conv ----
    for (int c0 = 0; c0 < 256; c0 += 128) {
        __syncthreads();
        for (int s = threadIdx.x; s < 3 * 34 * 16; s += 256) {
            int c16 = s & 15;
            int t2 = s >> 4;
            int col = t2 % 34;
            int rr = t2 / 34;
            int ih = oh - 1 + rr, iw = col - 1;
            int4 v = make_int4(0, 0, 0, 0);
            if ((unsigned)ih < 32u && (unsigned)iw < 32u)
                v = *(const int4*)&in[((((bb << 5) + ih) << 5) + iw) * 256 + c0 + (c16 << 3)];
            *(int4*)&win[(rr * 34 + col) * 132 + (c16 << 3)] = v;
        }
        __syncthreads();
        for (int kh = 0; kh < 3; ++kh) {
            #pragma unroll
            for (int kw = 0; kw < 3; ++kw) {
                #pragma unroll
                for (int cch = 0; cch < 4; ++cch) {
                    const unsigned short* ba = &win[(kh * 34 + m + kw) * 132 + (cch << 5) + (quad << 3)];
                    bf16x8 a0 = *(const bf16x8*)ba;
                    bf16x8 a1 = *(const bf16x8*)(ba + 16 * 132);
                    int cg = (c0 >> 5) + cch;
                    int wbase = (((kh * 3 + kw) * 8 + cg) * 256 + n0 + m) * 32 + (quad << 3);
                    bf16x8 b0 = *(const bf16x8*)&wf3[wbase];
                    bf16x8 b1 = *(const bf16x8*)&wf3[wbase + 16 * 32];
                    bf16x8 b2 = *(const bf16x8*)&wf3[wbase + 32 * 32];
                    bf16x8 b3 = *(const bf16x8*)&wf3[wbase + 48 * 32];
                    acc[0][0] = MFMA_B16(a0, b0, acc[0][0]);
                    acc[0][1] = MFMA_B16(a0, b1, acc[0][1]);
                    acc[0][2] = MFMA_B16(a0, b2, acc[0][2]);
                    acc[0][3] = MFMA_B16(a0, b3, acc[0][3]);
                    acc[1][0] = MFMA_B16(a1, b0, acc[1][0]);
                    acc[1][1] = MFMA_B16(a1, b1, acc[1][1]);
                    acc[1][2] = MFMA_B16(a1, b2, acc[1][2]);
                    acc[1][3] = MFMA_B16(a1, b3, acc[1][3]);
                }
            }
        }
    }

    // ---- relu -> LDS (mid aliases win: 32*264 = 8448 <= 13464 shorts) ----
    __syncthreads();
    unsigned short* mid = win;
    #pragma unroll
    for (int mt = 0; mt < 2; ++mt)
        #pragma unroll
        for (int nt = 0; nt < 4; ++nt)
            #pragma unroll
            for (int r = 0; r < 4; ++r) {
                int px = mt * 16 + quad * 4 + r;
                int col = n0 + nt * 16 + m;
                mid[px * 264 + col] = f2b(fmaxf(acc[mt][nt][r], 0.f));
            }
    __syncthreads();

    // ---- phase 2: 1x1 + residual ----
    f32x4 acc2[2][4];
    #pragma unroll
    for (int i = 0; i < 2; ++i)
        #pragma unroll
        for (int t = 0; t < 4; ++t) acc2[i][t] = z;
    #pragma unroll
    for (int cch = 0; cch < 8; ++cch) {
        bf16x8 a0 = *(const bf16x8*)&mid[m * 264 + (cch << 5) + (quad << 3)];
        bf16x8 a1 = *(const bf16x8*)&mid[(m + 16) * 264 + (cch << 5) + (quad << 3)];
        int wbase = (cch * 256 + n0 + m) * 32 + (quad << 3);
        bf16x8 b0 = *(const bf16x8*)&wf1[wbase];
        bf16x8 b1 = *(const bf16x8*)&wf1[wbase + 16 * 32];
        bf16x8 b2 = *(const bf16x8*)&wf1[wbase + 32 * 32];
        bf16x8 b3 = *(const bf16x8*)&wf1[wbase + 48 * 32];
        acc2[0][0] = MFMA_B16(a0, b0, acc2[0][0]);
        acc2[0][1] = MFMA_B16(a0, b1, acc2[0][1]);
        acc2[0][2] = MFMA_B16(a0, b2, acc2[0][2]);
        acc2[0][3] = MFMA_B16(a0, b3, acc2[0][3]);
        acc2[1][0] = MFMA_B16(a1, b0, acc2[1][0]);
        acc2[1][1] = MFMA_B16(a1, b1, acc2[1][1]);
        acc2[1][2] = MFMA_B16(a1, b2, acc2[1][2]);
        acc2[1][3] = MFMA_B16(a1, b3, acc2[1][3]);
    }
    int rowbase = blk << 13;   // 32 px * 256
    #pragma unroll
    for (int mt = 0; mt < 2; ++mt)
        #pragma unroll
        for (int nt = 0; nt < 4; ++nt)
            #pragma unroll
            for (int r = 0; r < 4; ++r) {
                int px = mt * 16 + quad * 4 + r;
                int col = n0 + nt * 16 + m;
                int idx = rowbase + (px << 8) + col;
                float v = acc2[mt][nt][r] + b2f(res[idx]);
                outb[idx] = f2b(v);
                if (f32out) outf[idx] = v;
            }
}

// ======================================================================
// mdeconv1 v4: ConvTranspose2d(256->256,k4,s2,p1)+bias+ReLU. Two
// same-parity oy rows per block, BOTH ox parities (R5 structure: 1024
// MFMAs/wave), channel-split staging (26.3 KB LDS -> 4 blocks/CU).
// grid = B*32 = 1024.
// ======================================================================
__global__ void __launch_bounds__(256, 4)
mdeconv1_k(const unsigned short* __restrict__ in, const unsigned short* __restrict__ wf,
           const float* __restrict__ bias, unsigned short* __restrict__ out)
{
    int blk = blockIdx.x;
    int bb = blk >> 5;
    int rem = blk & 31;
    int pp = rem >> 4;                  // oy parity group
    int i = rem & 15;
    int oy_a = pp + 4 * i;              // rows oy_a, oy_a+2
    int p = (oy_a + 1) & 1;
    int r0a = (oy_a + 1 - p) >> 1;
    int rbase = r0a - 1;                // input rows rbase..rbase+2
    int lane = threadIdx.x & 63;
    int n0 = (threadIdx.x >> 6) << 6;   // wave covers 64 cols
    int m = lane & 15, quad = lane >> 4;
    __shared__ __align__(16) unsigned short win[3 * 34 * 132];   // 26.3 KB

    for (int par = 0; par < 2; ++par) {
        f32x4 acc[2][2][4];   // [row][mt][nt]
        f32x4 z = {0.f, 0.f, 0.f, 0.f};
        #pragma unroll
        for (int a = 0; a < 2; ++a)
            #pragma unroll
            for (int i2 = 0; i2 < 2; ++i2)
                #pragma unroll
                for (int t = 0; t < 4; ++t) acc[a][i2][t] = z;

        for (int c0 = 0; c0 < 256; c0 += 128) {
            __syncthreads();
            for (int s = threadIdx.x; s < 3 * 34 * 16; s += 256) {
                int c16 = s & 15;
                int t2 = s >> 4;
                int col = t2 % 34;
                int rr = t2 / 34;
                int ih = rbase + rr, iw = col - 1;
                int4 v = make_int4(0, 0, 0, 0);
                if ((unsigned)ih < 32u && (unsigned)iw < 32u)
                    v = *(const int4*)&in[((((bb << 5) + ih) << 5) + iw) * 256 + c0 + (c16 << 3)];
                *(int4*)&win[(rr * 34 + col) * 132 + (c16 << 3)] = v;
            }
            __syncthreads();
            #pragma unroll
            for (int t = 0; t < 2; ++t) {
                int kh = p + 2 * t;
                #pragma unroll
                for (int u = 0; u < 2; ++u) {
                    int kw = (1 - par) + 2 * u;
                    int ixoff = par - u + 1;
                    #pragma unroll
                    for (int cch = 0; cch < 4; ++cch) {
                        const unsigned short* baA = &win[((1 - t) * 34 + m + ixoff) * 132 + (cch << 5) + (quad << 3)];
                        const unsigned short* baB = &win[((2 - t) * 34 + m + ixoff) * 132 + (cch << 5) + (quad << 3)];
                        bf16x8 a00 = *(const bf16x8*)baA;
                        bf16x8 a01 = *(const bf16x8*)(baA + 16 * 132);
                        bf16x8 a10 = *(const bf16x8*)baB;
                        bf16x8 a11 = *(const bf16x8*)(baB + 16 * 132);
                        int cg = (c0 >> 5) + cch;
                        int wbase = ((((kh << 2) + kw) * 8 + cg) * 256 + n0 + m) * 32 + (quad << 3);
                        bf16x8 b0 = *(const bf16x8*)&wf[wbase];
                        bf16x8 b1 = *(const bf16x8*)&wf[wbase + 16 * 32];
                        bf16x8 b2 = *(const bf16x8*)&wf[wbase + 32 * 32];
                        bf16x8 b3 = *(const bf16x8*)&wf[wbase + 48 * 32];
                        acc[0][0][0] = MFMA_B16(a00, b0, acc[0][0][0]);
                        acc[0][0][1] = MFMA_B16(a00, b1, acc[0][0][1]);
                        acc[0][0][2] = MFMA_B16(a00, b2, acc[0][0][2]);
                        acc[0][0][3] = MFMA_B16(a00, b3, acc[0][0][3]);
                        acc[0][1][0] = MFMA_B16(a01, b0, acc[0][1][0]);
                        acc[0][1][1] = MFMA_B16(a01, b1, acc[0][1][1]);
                        acc[0][1][2] = MFMA_B16(a01, b2, acc[0][1][2]);
                        acc[0][1][3] = MFMA_B16(a01, b3, acc[0][1][3]);
                        acc[1][0][0] = MFMA_B16(a10, b0, acc[1][0][0]);
                        acc[1][0][1] = MFMA_B16(a10, b1, acc[1][0][1]);
                        acc[1][0][2] = MFMA_B16(a10, b2, acc[1][0][2]);
                        acc[1][0][3] = MFMA_B16(a10, b3, acc[1][0][3]);
                        acc[1][1][0] = MFMA_B16(a11, b0, acc[1][1][0]);
                        acc[1][1][1] = MFMA_B16(a11, b1, acc[1][1][1]);
                        acc[1][1][2] = MFMA_B16(a11, b2, acc[1][1][2]);
                        acc[1][1][3] = MFMA_B16(a11, b3, acc[1][1][3]);
                    }
                }
            }
        }
        #pragma unroll
        for (int row = 0; row < 2; ++row) {
            int oy = oy_a + 2 * row;
            #pragma unroll
            for (int mt = 0; mt < 2; ++mt)
                #pragma unroll
                for (int nt = 0; nt < 4; ++nt) {
                    int col = n0 + nt * 16 + m;
                    float bs = bias[col];
                    #pragma unroll
                    for (int r = 0; r < 4; ++r) {
                        int ox = 2 * (mt * 16 + quad * 4 + r) + par;
                        float v = fmaxf(acc[row][mt][nt][r] + bs, 0.f);
                        out[((((bb << 6) + oy) << 6) + ox) * 256 + col] = f2b(v);
                    }
                }
        }
    }
}

// ======================================================================
// vqm: MFMA VQ + exact fp32 gather/loss. grid = B*32.
// ======================================================================
__global__ void __launch_bounds__(256, 2)
vqm_k(const unsigned short* __restrict__ zeb, const float* __restrict__ zef,
      const unsigned short* __restrict__ embF, const float* __restrict__ embed,
      const float* __restrict__ nrm, unsigned short* __restrict__ zq,
      float* __restrict__ lacc)
{
    int bh = blockIdx.x;
    int tid = threadIdx.x;
    int lane = tid & 63;
    int wv = tid >> 6;
    int m = lane & 15, quad = lane >> 4;
    __shared__ __align__(16) unsigned short win[32 * 264];
    __shared__ float bvv[4][32];
    __shared__ int   bii[4][32];
    __shared__ int   bidx[32];
    int rowbase = bh << 13;
    for (int s = tid; s < 32 * 32; s += 256) {
        int c8 = s & 31, px = s >> 5;
        *(int4*)&win[px * 264 + (c8 << 3)] = *(const int4*)&zeb[rowbase + (px << 8) + (c8 << 3)];
    }
    __syncthreads();

    f32x4 acc[2][8];
    f32x4 z = {0.f, 0.f, 0.f, 0.f};
    #pragma unroll
    for (int i = 0; i < 2; ++i)
        #pragma unroll
        for (int j = 0; j < 8; ++j) acc[i][j] = z;

    #pragma unroll
    for (int cch = 0; cch < 8; ++cch) {
        bf16x8 a0 = *(const bf16x8*)&win[m * 264 + (cch << 5) + (quad << 3)];
        bf16x8 a1 = *(const bf16x8*)&win[(m + 16) * 264 + (cch << 5) + (quad << 3)];
        #pragma unroll
        for (int nt = 0; nt < 8; ++nt) {
            bf16x8 b = *(const bf16x8*)&embF[((cch << 9) + (wv << 7) + (nt << 4) + m) * 32 + (quad << 3)];
            acc[0][nt] = MFMA_B16(a0, b, acc[0][nt]);
            acc[1][nt] = MFMA_B16(a1, b, acc[1][nt]);
        }
    }

    float nv[8];
    #pragma unroll
    for (int nt = 0; nt < 8; ++nt) nv[nt] = nrm[(wv << 7) + (nt << 4) + m];

    #pragma unroll
    for (int mt = 0; mt < 2; ++mt)
        #pragma unroll
        for (int r = 0; r < 4; ++r) {
            float bv = 1e30f;
            int bi = 0x7fffffff;
            #pragma unroll
            for (int nt = 0; nt < 8; ++nt) {
                float d = nv[nt] - 2.f * acc[mt][nt][r];
                int n = (wv << 7) + (nt << 4) + m;
                if (d < bv || (d == bv && n < bi)) { bv = d; bi = n; }
            }
            #pragma unroll
            for (int off = 1; off < 16; off <<= 1) {
                float ov = __shfl_xor(bv, off);
                int oi = __shfl_xor(bi, off);
                if (ov < bv || (ov == bv && oi < bi)) { bv = ov; bi = oi; }
            }
            if (m == 0) {
                int px = mt * 16 + quad * 4 + r;
                bvv[wv][px] = bv;
                bii[wv][px] = bi;
            }
        }
    __syncthreads();
    if (tid < 32) {
        float bv = bvv[0][tid];
        int bi = bii[0][tid];
        #pragma unroll
        for (int w2 = 1; w2 < 4; ++w2) {
            float ov = bvv[w2][tid];
            int oi = bii[w2][tid];
            if (ov < bv || (ov == bv && oi < bi)) { bv = ov; bi = oi; }
        }
        bidx[tid] = bi;
    }
    __syncthreads();

    float lsum = 0.f;
    #pragma unroll
    for (int j = 0; j < 8; ++j) {
        int px = (wv << 3) + j;
        int bi = bidx[px];
        int pix = (bh << 5) + px;
        const float4 e = *(const float4*)&embed[bi * 256 + (lane << 2)];
        const float4 zv = *(const float4*)&zef[(pix << 8) + (lane << 2)];
        ushort4 eq;
        eq.x = f2b(e.x); eq.y = f2b(e.y); eq.z = f2b(e.z); eq.w = f2b(e.w);
        *(ushort4*)&zq[(pix << 8) + (lane << 2)] = eq;
        float dx = zv.x - e.x, dy = zv.y - e.y, dz = zv.z - e.z, dw = zv.w - e.w;
        lsum += dx * dx + dy * dy + dz * dz + dw * dw;
    }
    #pragma unroll
    for (int off = 1; off < 64; off <<= 1) lsum += __shfl_xor(lsum, off);
    if (lane == 0) atomicAdd(lacc, lsum);
}

// ======================================================================
// mdec2a: deconv2 pass 1 — Y[B*64*64, 48] = X[.,256] x Wg[256,48]
// ======================================================================
__global__ void __launch_bounds__(256, 4)
mdec2a_k(const unsigned short* __restrict__ in, const unsigned short* __restrict__ wg,
         float* __restrict__ Y)
{
    int tid = threadIdx.x;
    int lane = tid & 63;
    int wv = tid >> 6;
    int m = lane & 15, quad = lane >> 4;
    __shared__ __align__(16) unsigned short win[64 * 264];
    int pxbase = blockIdx.x << 6;
    for (int s = tid; s < 64 * 32; s += 256) {
        int c8 = s & 31, px = s >> 5;
        *(int4*)&win[px * 264 + (c8 << 3)] = *(const int4*)&in[((pxbase + px) << 8) + (c8 << 3)];
    }
    __syncthreads();
    f32x4 acc[3];
    f32x4 z = {0.f, 0.f, 0.f, 0.f};
    acc[0] = z; acc[1] = z; acc[2] = z;
    #pragma unroll
    for (int cch = 0; cch < 8; ++cch) {
        bf16x8 a = *(const bf16x8*)&win[((wv << 4) + m) * 264 + (cch << 5) + (quad << 3)];
        #pragma unroll
        for (int nt = 0; nt < 3; ++nt) {
            bf16x8 b = *(const bf16x8*)&wg[(cch * 48 + nt * 16 + m) * 32 + (quad << 3)];
            acc[nt] = MFMA_B16(a, b, acc[nt]);
        }
    }
    #pragma unroll
    for (int nt = 0; nt < 3; ++nt)
        #pragma unroll
        for (int r = 0; r < 4; ++r) {
            int px = pxbase + (wv << 4) + quad * 4 + r;
            Y[px * 48 + nt * 16 + m] = acc[nt][r];
        }
}

// ======================================================================
// dec2b: deconv2 pass 2 — gather taps, +bias, sigmoid, NCHW out + losses.
// ======================================================================
__global__ void dec2b_k(const float* __restrict__ Y, const float* __restrict__ bias,
                        const float* __restrict__ lacc, float* __restrict__ out)
{
    if (blockIdx.x == 0 && threadIdx.x == 0) {
        float mloss = lacc[0] * (1.0f / 32768.0f);
        out[1572864] = mloss;
        out[1572865] = mloss;
    }
    int idx = blockIdx.x * 256 + threadIdx.x;
    int b = idx >> 14;
    int rem = idx & 16383;
    int oy = rem >> 7;
    int ox = rem & 127;
    int p = (oy + 1) & 1;
    int q = (ox + 1) & 1;
    float acc0 = bias[0], acc1 = bias[1], acc2 = bias[2];
    #pragma unroll
    for (int t = 0; t < 2; ++t) {
        int kh = p + 2 * t;
        int ih = (oy + 1 - kh) >> 1;
        if ((unsigned)ih >= 64u) continue;
        #pragma unroll
        for (int u = 0; u < 2; ++u) {
            int kw = q + 2 * u;
            int iw = (ox + 1 - kw) >> 1;
            if ((unsigned)iw >= 64u) continue;
            int base = ((((b << 6) + ih) << 6) + iw) * 48 + ((kh << 2) + kw) * 3;
            acc0 += Y[base];
            acc1 += Y[base + 1];
            acc2 += Y[base + 2];
        }
    }
    int obase = (b * 3 << 14) + (oy << 7) + ox;
    out[obase]           = 1.f / (1.f + expf(-acc0));
    out[obase + 16384]   = 1.f / (1.f + expf(-acc1));
    out[obase + 32768]   = 1.f / (1.f + expf(-acc2));
}

// ======================================================================
extern "C" void kernel_launch(void* const* d_in, const int* in_sizes, int n_in,
                              void* d_out, int out_size, void* d_ws, size_t ws_size,
                              hipStream_t stream)
{
    (void)in_sizes; (void)n_in; (void)out_size; (void)ws_size;
    const float* x      = (const float*)d_in[0];
    const float* embed  = (const float*)d_in[1];
    const float* e_w1   = (const float*)d_in[2];
    const float* e_w2   = (const float*)d_in[3];
    const float* e_r1a  = (const float*)d_in[4];
    const float* e_r1b  = (const float*)d_in[5];
    const float* e_r2a  = (const float*)d_in[6];
    const float* e_r2b  = (const float*)d_in[7];
    const float* d_r1a  = (const float*)d_in[8];
    const float* d_r1b  = (const float*)d_in[9];
    const float* d_r2a  = (const float*)d_in[10];
    const float* d_r2b  = (const float*)d_in[11];
    const float* dt1_w  = (const float*)d_in[12];
    const float* dt1_b  = (const float*)d_in[13];
    const float* dt2_w  = (const float*)d_in[14];
    const float* dt2_b  = (const float*)d_in[15];
    float* outp = (float*)d_out;

    // ---- workspace layout ----
    char* base = (char*)d_ws;
    size_t off = 0;
    auto alloc = [&](size_t bytes) { char* p = base + off; off += (bytes + 255) & ~size_t(255); return p; };
    unsigned short* A0b = (unsigned short*)alloc(67108864);  // (B,64,64,256) bf16
    float*          A1f = (float*)alloc(33554432);           // ze fp32; later Y
    unsigned short* L0  = (unsigned short*)alloc(16777216);
    unsigned short* L1  = (unsigned short*)alloc(16777216);
    unsigned short* Wf  = (unsigned short*)alloc(9437184);   // 10 frag-ordered weights
    unsigned short* Wg  = (unsigned short*)alloc(24576);     // deconv2 frag weights
    unsigned short* EmbF = (unsigned short*)alloc(262144);   // codebook frag bf16
    unsigned short* WgC = (unsigned short*)alloc(32768);     // conv1 frag weights
    float* Nrm  = (float*)alloc(2048);
    float* Lacc = (float*)alloc(64);
    float* Y = A1f;   // alias: ze dead after vqm_k

    unsigned short* Wf_ew2  = Wf;
    unsigned short* Wf_er1a = Wf + 1048576;
    unsigned short* Wf_er1b = Wf + 1638400;
    unsigned short* Wf_er2a = Wf + 1703936;
    unsigned short* Wf_er2b = Wf + 2293760;
    unsigned short* Wf_dr1a = Wf + 2359296;
    unsigned short* Wf_dr1b = Wf + 2949120;
    unsigned short* Wf_dr2a = Wf + 3014656;
    unsigned short* Wf_dr2b = Wf + 3604480;
    unsigned short* Wf_dt1  = Wf + 3670016;

    PermfArgs pa;
    const float* srcs[10] = {e_w2, e_r1a, e_r1b, e_r2a, e_r2b, d_r1a, d_r1b, d_r2a, d_r2b, dt1_w};
    int kws[10] = {4, 3, 1, 3, 1, 3, 1, 3, 1, 4};
    int sos[10] = {4096, 2304, 256, 2304, 256, 2304, 256, 2304, 256, 16};
    int sis[10] = {16, 9, 1, 9, 1, 9, 1, 9, 1, 4096};
    int shs[10] = {4, 3, 0, 3, 0, 3, 0, 3, 0, 4};
    int sws[10] = {1, 1, 0, 1, 0, 1, 0, 1, 0, 1};
    int cums[11] = {0, 1048576, 1638400, 1703936, 2293760, 2359296,
                    2949120, 3014656, 3604480, 3670016, 4718592};
    for (int k = 0; k < 10; ++k) {
        pa.src[k] = srcs[k]; pa.kw[k] = kws[k]; pa.so[k] = sos[k];
        pa.si[k] = sis[k]; pa.sh[k] = shs[k]; pa.sw[k] = sws[k];
        pa.cum[k] = cums[k];
    }
    pa.cum[10] = cums[10];

    prep_all_k<<<19185, 256, 0, stream>>>(pa, Wf, dt2_w, Wg, embed, EmbF, e_w1, WgC, Nrm, Lacc);

    // ---- encoder ----
    conv1m_k<<<32 * 64, 256, 0, stream>>>(x, WgC, A0b);
    mconv2_k<<<32 * 32, 256, 0, stream>>>(A0b, Wf_ew2, L1);                    // h
    mres_k<<<32 * 32, 256, 0, stream>>>(L1, Wf_er1a, Wf_er1b, L1, L0, nullptr, 0);   // r1 -> L0
    mres_k<<<32 * 32, 256, 0, stream>>>(L0, Wf_er2a, Wf_er2b, L0, L1, A1f, 1);       // ze -> L1 (bf16) + A1f (fp32)

    // ---- VQ ----
    vqm_k<<<32 * 32, 256, 0, stream>>>(L1, A1f, EmbF, embed, Nrm, L1, Lacc);   // zq -> L1

    // ---- decoder ----
    mres_k<<<32 * 32, 256, 0, stream>>>(L1, Wf_dr1a, Wf_dr1b, L1, L0, nullptr, 0);   // d1 -> L0
    mres_k<<<32 * 32, 256, 0, stream>>>(L0, Wf_dr2a, Wf_dr2b, L0, L1, nullptr, 0);   // d2 -> L1
    mdeconv1_k<<<32 * 32, 256, 0, stream>>>(L1, Wf_dt1, dt1_b, A0b);
    mdec2a_k<<<2048, 256, 0, stream>>>(A0b, Wg, Y);
    dec2b_k<<<2048, 256, 0, stream>>>(Y, dt2_b, Lacc, outp);
}

// Round 9
// 856.167 us; speedup vs baseline: 1.0284x; 1.0063x over previous
//
#include <hip/hip_runtime.h>

// ======================================================================
// VQ-VAE forward, all-MFMA. B=32, CIN=3, IMG=128, D=256, K=512.
// NHWC bf16 activations. KEY FIX (R9): all MFMA epilogues stage D-tiles
// through LDS and store 16B/lane coalesced (the direct D-layout store is
// 2B/lane partial-sector scatter -> 10-13x HBM write amplification,
// measured 318MB vs 33MB useful on mdeconv1). res-reads coalesced too.
// Weights frag-ordered Wf[khkw][cch][n][32]. MFMA 16x16x32 bf16:
// A[m=lane&15][k=quad*8+j], B[n][k], D col=lane&15, row=quad*4+reg.
// ======================================================================

typedef __attribute__((ext_vector_type(8))) short bf16x8;
typedef __attribute__((ext_vector_type(4))) float f32x4;
#define MFMA_B16(a, b, c) __builtin_amdgcn_mfma_f32_16x16x32_bf16(a, b, c, 0, 0, 0)

__device__ inline unsigned short f2b(float f) {
    unsigned int u = __float_as_uint(f);
    unsigned int r = u + 0x7fffu + ((u >> 16) & 1u);
    return (unsigned short)(r >> 16);
}
__device__ inline float b2f(unsigned short u) {
    return __uint_as_float(((unsigned int)u) << 16);
}

// ======================================================================
// prep_all: [0,18432) frag-permute 10 conv weights; rest misc.
// ======================================================================
struct PermfArgs {
    const float* src[10];
    int kw[10];
    int so[10], si[10], sh[10], sw[10];
    int cum[11];
};

__global__ void prep_all_k(PermfArgs a, unsigned short* __restrict__ dst,
                           const float* __restrict__ dt2_w, unsigned short* __restrict__ wg,
                           const float* __restrict__ embed, unsigned short* __restrict__ embF,
                           const float* __restrict__ e_w1, unsigned short* __restrict__ wgc,
                           float* __restrict__ nrm, float* __restrict__ lacc)
{
    int blkid = blockIdx.x;
    int tid = threadIdx.x;
    if (blkid < 18432) {
        int gid = blkid * 256 + tid;
        if (gid >= a.cum[10]) return;
        int seg = 0;
        while (seg < 9 && gid >= a.cum[seg + 1]) ++seg;
        int l = gid - a.cum[seg];
        int q = l & 31;
        int n = (l >> 5) & 255;
        int rest = l >> 13;
        int cch = rest & 7;
        int khkw = rest >> 3;
        int kh = khkw / a.kw[seg], kw = khkw % a.kw[seg];
        int ci = cch * 32 + q;
        dst[gid] = f2b(a.src[seg][n * a.so[seg] + ci * a.si[seg] + kh * a.sh[seg] + kw * a.sw[seg]]);
        return;
    }
    int blk = blkid - 18432;
    if (blk < 48) {
        int idx = blk * 256 + tid;
        int q = idx & 31;
        int n = (idx >> 5) % 48;
        int cch = idx / (48 * 32);
        int ci = cch * 32 + q;
        int oc = n % 3, khkw = n / 3;
        int kh = khkw >> 2, kw = khkw & 3;
        wg[idx] = f2b(dt2_w[ci * 48 + oc * 16 + kh * 4 + kw]);
    } else if (blk < 560) {
        int idx = (blk - 48) * 256 + tid;
        int q = idx & 31;
        int n = (idx >> 5) & 511;
        int cch = idx >> 14;
        embF[idx] = f2b(embed[n * 256 + cch * 32 + q]);
    } else if (blk < 624) {
        int idx = (blk - 560) * 256 + tid;
        int q = idx & 31;
        int n = (idx >> 5) & 255;
        int kt = idx >> 13;
        int k = kt * 32 + q;
        float v = 0.f;
        if (k < 48) {
            int ci = k >> 4, kh = (k >> 2) & 3, kwv = k & 3;
            v = e_w1[n * 48 + ci * 16 + kh * 4 + kwv];
        }
        wgc[idx] = f2b(v);
    } else if (blk < 752) {
        int row = (blk - 624) * 4 + (tid >> 6);
        int lane = tid & 63;
        float s = 0.f;
        #pragma unroll
        for (int c = 0; c < 256; c += 64) {
            float v = embed[row * 256 + c + lane];
            s += v * v;
        }
        #pragma unroll
        for (int off = 1; off < 64; off <<= 1) s += __shfl_xor(s, off);
        if (lane == 0) nrm[row] = s;
    } else {
        if (tid == 0) lacc[0] = 0.f;
    }
}

// ======================================================================
// conv1m: MFMA im2col conv1. x NCHW fp32 -> NHWC bf16 (B,64,64,256),
// k4 s2 p1, ReLU. grid = B*64. Coalesced LDS-staged output.
// ======================================================================
__global__ void __launch_bounds__(256, 4)
conv1m_k(const float* __restrict__ x, const unsigned short* __restrict__ wgc,
         unsigned short* __restrict__ out)
{
    int bh = blockIdx.x;
    int b = bh >> 6, oh = bh & 63;
    int tid = threadIdx.x;
    int lane = tid & 63, wv = tid >> 6;
    int m = lane & 15, quad = lane >> 4;
    __shared__ float xrow[3][4][130];
    __shared__ __align__(16) unsigned short imc[64 * 72];
    __shared__ __align__(16) unsigned short obuf[32 * 264];
    for (int s = tid; s < 1560; s += 256) {
        int col = s % 130;
        int t = s / 130;
        int r = t & 3;
        int c = t >> 2;
        int ih = 2 * oh - 1 + r, iw = col - 1;
        float v = 0.f;
        if ((unsigned)ih < 128u && (unsigned)iw < 128u)
            v = x[(((b * 3 + c) << 7) + ih) * 128 + iw];
        xrow[c][r][col] = v;
    }
    __syncthreads();
    for (int s = tid; s < 4096; s += 256) {
        int px = s >> 6, k = s & 63;
        float v = 0.f;
        if (k < 48) {
            int ci = k >> 4, kh = (k >> 2) & 3, kw = k & 3;
            v = xrow[ci][kh][2 * px + kw];
        }
        imc[px * 72 + k] = f2b(v);
    }
    __syncthreads();
    f32x4 acc[16];
    f32x4 z = {0.f, 0.f, 0.f, 0.f};
    #pragma unroll
    for (int i = 0; i < 16; ++i) acc[i] = z;
    bf16x8 a0 = *(const bf16x8*)&imc[((wv << 4) + m) * 72 + (quad << 3)];
    bf16x8 a1 = *(const bf16x8*)&imc[((wv << 4) + m) * 72 + 32 + (quad << 3)];
    #pragma unroll
    for (int nt = 0; nt < 16; ++nt) {
        bf16x8 b0 = *(const bf16x8*)&wgc[(nt * 16 + m) * 32 + (quad << 3)];
        bf16x8 b1 = *(const bf16x8*)&wgc[(256 + nt * 16 + m) * 32 + (quad << 3)];
        acc[nt] = MFMA_B16(a0, b0, acc[nt]);
        acc[nt] = MFMA_B16(a1, b1, acc[nt]);
    }
    // coalesced epilogue: two halves of 32 px
    for (int h = 0; h < 2; ++h) {
        __syncthreads();
        if ((wv >> 1) == h) {
            #pragma unroll
            for (int nt = 0; nt < 16; ++nt)
                #pragma unroll
                for (int r = 0; r < 4; ++r) {
                    int pxl = ((wv & 1) << 4) + quad * 4 + r;
                    obuf[pxl * 264 + nt * 16 + m] = f2b(fmaxf(acc[nt][r], 0.f));
                }
        }
        __syncthreads();
        int pxl2 = tid >> 3, seg = tid & 7;
        int gp = (bh << 6) + 32 * h + pxl2;
        #pragma unroll
        for (int u = 0; u < 4; ++u)
            *(int4*)&out[(gp << 8) + seg * 32 + u * 8] = *(int4*)&obuf[pxl2 * 264 + seg * 32 + u * 8];
    }
}

// ======================================================================
// mconv2: k4 s2 p1, (B,64,64,256)->(B,32,32,256), ReLU. M=64, N=128.
// grid = B*16*2 = 1024. Coalesced LDS-staged output.
// ======================================================================
__global__ void __launch_bounds__(256, 4)
mconv2_k(const unsigned short* __restrict__ in, const unsigned short* __restrict__ wf,
         unsigned short* __restrict__ out)
{
    int blk = blockIdx.x;
    int bb = blk >> 5;
    int rem = blk & 31;
    int j = rem >> 1;
    int nh = rem & 1;
    int tid = threadIdx.x;
    int lane = tid & 63;
    int wv = tid >> 6;
    int n0 = (nh << 7) + (wv << 5);
    int m = lane & 15, quad = lane >> 4;
    __shared__ __align__(16) unsigned short win[2 * 66 * 132];  // 34.8 KB
    f32x4 acc[2][2][2];   // [row][mt][nt]
    f32x4 z = {0.f, 0.f, 0.f, 0.f};
    #pragma unroll
    for (int a = 0; a < 2; ++a)
        #pragma unroll
        for (int i = 0; i < 2; ++i)
            #pragma unroll
            for (int t = 0; t < 2; ++t) acc[a][i][t] = z;

    for (int c0 = 0; c0 < 256; c0 += 128) {
        for (int kh = 0; kh < 4; ++kh) {
            __syncthreads();
            for (int s = tid; s < 2 * 66 * 16; s += 256) {
                int c16 = s & 15;
                int t2 = s >> 4;
                int col = t2 % 66;
                int rr = t2 / 66;
                int ih = 4 * j - 1 + kh + 2 * rr, iw = col - 1;
                int4 v = make_int4(0, 0, 0, 0);
                if ((unsigned)ih < 64u && (unsigned)iw < 64u)
                    v = *(const int4*)&in[((((bb << 6) + ih) << 6) + iw) * 256 + c0 + (c16 << 3)];
                int cs = (col >> 1) + (col & 1) * 33;
                *(int4*)&win[(rr * 66 + cs) * 132 + (c16 << 3)] = v;
            }
            __syncthreads();
            #pragma unroll
            for (int kw = 0; kw < 4; ++kw) {
                int csoff = (kw >> 1) + (kw & 1) * 33;
                #pragma unroll
                for (int cch = 0; cch < 4; ++cch) {
                    bf16x8 a00 = *(const bf16x8*)&win[(m + csoff) * 132 + (cch << 5) + (quad << 3)];
                    bf16x8 a01 = *(const bf16x8*)&win[(m + 16 + csoff) * 132 + (cch << 5) + (quad << 3)];
                    bf16x8 a10 = *(const bf16x8*)&win[(66 + m + csoff) * 132 + (cch << 5) + (quad << 3)];
                    bf16x8 a11 = *(const bf16x8*)&win[(66 + m + 16 + csoff) * 132 + (cch << 5) + (quad << 3)];
                    int cg = (c0 >> 5) + cch;
                    int wbase = ((((kh << 2) + kw) * 8 + cg) * 256 + n0 + m) * 32 + (quad << 3);
                    bf16x8 b0 = *(const bf16x8*)&wf[wbase];
                    bf16x8 b1 = *(const bf16x8*)&wf[wbase + 16 * 32];
                    acc[0][0][0] = MFMA_B16(a00, b0, acc[0][0][0]);
                    acc[0][0][1] = MFMA_B16(a00, b1, acc[0][0][1]);
                    acc[0][1][0] = MFMA_B16(a01, b0, acc[0][1][0]);
                    acc[0][1][1] = MFMA_B16(a01, b1, acc[0][1][1]);
                    acc[1][0][0] = MFMA_B16(a10, b0, acc[1][0][0]);
                    acc[1][0][1] = MFMA_B16(a10, b1, acc[1][0][1]);
                    acc[1][1][0] = MFMA_B16(a11, b0, acc[1][1][0]);
                    acc[1][1][1] = MFMA_B16(a11, b1, acc[1][1][1]);
                }
            }
        }
    }
    // coalesced epilogue: per output row, stage 32px x 128col in LDS
    for (int row = 0; row < 2; ++row) {
        __syncthreads();
        #pragma unroll
        for (int mt = 0; mt < 2; ++mt)
            #pragma unroll
            for (int nt = 0; nt < 2; ++nt)
                #pragma unroll
                for (int r = 0; r < 4; ++r) {
                    int px = mt * 16 + quad * 4 + r;
                    int lcol = (wv << 5) + nt * 16 + m;
                    win[px * 136 + lcol] = f2b(fmaxf(acc[row][mt][nt][r], 0.f));
                }
        __syncthreads();
        int oh = 2 * j + row;
        int px2 = tid >> 3, seg = tid & 7;
        int gb = ((((bb << 5) + oh) << 5) + px2) * 256 + (nh << 7) + seg * 16;
        *(int4*)&out[gb]     = *(int4*)&win[px2 * 136 + seg * 16];
        *(int4*)&out[gb + 8] = *(int4*)&win[px2 * 136 + seg * 16 + 8];
    }
}

// ======================================================================
// mres: fused residual block: out = 1x1(relu(3x3(in))) + res. M=32.
// grid = B*32 = 1024. Coalesced res-read + output (bf16 and optional fp32).
// ======================================================================
__global__ void __launch_bounds__(256, 4)
mres_k(const unsigned short* __restrict__ in, const unsigned short* __restrict__ wf3,
       const unsigned short* __restrict__ wf1, const unsigned short* __restrict__ res,
       unsigned short* __restrict__ outb, float* __restrict__ outf, int f32out)
{
    int blk = blockIdx.x;            // bb*32 + oh
    int bb = blk >> 5, oh = blk & 31;
    int tid = threadIdx.x;
    int lane = tid & 63;
    int n0 = (tid >> 6) << 6;
    int m = lane & 15, quad = lane >> 4;
    __shared__ __align__(16) unsigned short win[3 * 34 * 132];  // 26.9 KB; aliased as mid[32*264]
    f32x4 acc[2][4];
    f32x4 z = {0.f, 0.f, 0.f, 0.f};
    #pragma unroll
    for (int i = 0; i < 2; ++i)
        #pragma unroll
        for (int t = 0; t < 4; ++t) acc[i][t] = z;

    // ---- phase 1: 3x3 conv ----
    for (int c0 = 0; c0 < 256; c0 += 128) {
        __syncthreads();
        for (int s = tid; s < 3 * 34 * 16; s += 256) {
            int c16 = s & 15;
            int t2 = s >> 4;
            int col = t2 % 34;
            int rr = t2 / 34;
            int ih = oh - 1 + rr, iw = col - 1;
            int4 v = make_int4(0, 0, 0, 0);
            if ((unsigned)ih < 32u && (unsigned)iw < 32u)
                v = *(const int4*)&in[((((bb << 5) + ih) << 5) + iw) * 256 + c0 + (c16 << 3)];
            *(int4*)&win[(rr * 34 + col) * 132 + (c16 << 3)] = v;
        }
        __syncthreads();
        for (int kh = 0; kh < 3; ++kh) {
            #pragma unroll
            for (int kw = 0; kw < 3; ++kw) {
                #pragma unroll
                for (int cch = 0; cch < 4; ++cch) {
                    const unsigned short* ba = &win[(kh * 34 + m + kw) * 132 + (cch << 5) + (quad << 3)];
                    bf16x8 a0 = *(const bf16x8*)ba;
                    bf16x8 a1 = *(const bf16x8*)(ba + 16 * 132);
                    int cg = (c0 >> 5) + cch;
                    int wbase = (((kh * 3 + kw) * 8 + cg) * 256 + n0 + m) * 32 + (quad << 3);
                    bf16x8 b0 = *(const bf16x8*)&wf3[wbase];
                    bf16x8 b1 = *(const bf16x8*)&wf3[wbase + 16 * 32];
                    bf16x8 b2 = *(const bf16x8*)&wf3[wbase + 32 * 32];
                    bf16x8 b3 = *(const bf16x8*)&wf3[wbase + 48 * 32];
                    acc[0][0] = MFMA_B16(a0, b0, acc[0][0]);
                    acc[0][1] = MFMA_B16(a0, b1, acc[0][1]);
                    acc[0][2] = MFMA_B16(a0, b2, acc[0][2]);
                    acc[0][3] = MFMA_B16(a0, b3, acc[0][3]);
                    acc[1][0] = MFMA_B16(a1, b0, acc[1][0]);
                    acc[1][1] = MFMA_B16(a1, b1, acc[1][1]);
                    acc[1][2] = MFMA_B16(a1, b2, acc[1][2]);
                    acc[1][3] = MFMA_B16(a1, b3, acc[1][3]);
                }
            }
        }
    }

    // ---- relu -> LDS (mid aliases win) ----
    __syncthreads();
    unsigned short* mid = win;
    #pragma unroll
    for (int mt = 0; mt < 2; ++mt)
        #pragma unroll
        for (int nt = 0; nt < 4; ++nt)
            #pragma unroll
            for (int r = 0; r < 4; ++r) {
                int px = mt * 16 + quad * 4 + r;
                int col = n0 + nt * 16 + m;
                mid[px * 264 + col] = f2b(fmaxf(acc[mt][nt][r], 0.f));
            }
    __syncthreads();

    // ---- phase 2: 1x1 ----
    f32x4 acc2[2][4];
    #pragma unroll
    for (int i = 0; i < 2; ++i)
        #pragma unroll
        for (int t = 0; t < 4; ++t) acc2[i][t] = z;
    #pragma unroll
    for (int cch = 0; cch < 8; ++cch) {
        bf16x8 a0 = *(const bf16x8*)&mid[m * 264 + (cch << 5) + (quad << 3)];
        bf16x8 a1 = *(const bf16x8*)&mid[(m + 16) * 264 + (cch << 5) + (quad << 3)];
        int wbase = (cch * 256 + n0 + m) * 32 + (quad << 3);
        bf16x8 b0 = *(const bf16x8*)&wf1[wbase];
        bf16x8 b1 = *(const bf16x8*)&wf1[wbase + 16 * 32];
        bf16x8 b2 = *(const bf16x8*)&wf1[wbase + 32 * 32];
        bf16x8 b3 = *(const bf16x8*)&wf1[wbase + 48 * 32];
        acc2[0][0] = MFMA_B16(a0, b0, acc2[0][0]);
        acc2[0][1] = MFMA_B16(a0, b1, acc2[0][1]);
        acc2[0][2] = MFMA_B16(a0, b2, acc2[0][2]);
        acc2[0][3] = MFMA_B16(a0, b3, acc2[0][3]);
        acc2[1][0] = MFMA_B16(a1, b0, acc2[1][0]);
        acc2[1][1] = MFMA_B16(a1, b1, acc2[1][1]);
        acc2[1][2] = MFMA_B16(a1, b2, acc2[1][2]);
        acc2[1][3] = MFMA_B16(a1, b3, acc2[1][3]);
    }
    // ---- coalesced epilogue: acc2 -> LDS (bf16), then res-add + stores ----
    __syncthreads();
    #pragma unroll
    for (int mt = 0; mt < 2; ++mt)
        #pragma unroll
        for (int nt = 0; nt < 4; ++nt)
            #pragma unroll
            for (int r = 0; r < 4; ++r) {
                int px = mt * 16 + quad * 4 + r;
                int col = n0 + nt * 16 + m;
                mid[px * 264 + col] = f2b(acc2[mt][nt][r]);
            }
    __syncthreads();
    int rowbase = blk << 13;   // 32 px * 256
    int px2 = tid >> 3, seg = tid & 7;
    #pragma unroll
    for (int u = 0; u < 4; ++u) {
        int c0 = seg * 32 + u * 8;
        int gb = rowbase + (px2 << 8) + c0;
        int4 av4 = *(const int4*)&mid[px2 * 264 + c0];
        int4 rv4 = *(const int4*)&res[gb];
        const unsigned short* ap = (const unsigned short*)&av4;
        const unsigned short* rp = (const unsigned short*)&rv4;
        float v[8];
        unsigned short ob[8];
        #pragma unroll
        for (int j2 = 0; j2 < 8; ++j2) {
            v[j2] = b2f(ap[j2]) + b2f(rp[j2]);
            ob[j2] = f2b(v[j2]);
        }
        *(int4*)&outb[gb] = *(int4*)ob;
        if (f32out) {
            *(float4*)&outf[gb] = make_float4(v[0], v[1], v[2], v[3]);
            *(float4*)&outf[gb + 4] = make_float4(v[4], v[5], v[6], v[7]);
        }
    }
}

// ======================================================================
// mdeconv1: ConvTranspose2d(256->256,k4,s2,p1)+bias+ReLU. Two same-parity
// oy rows per block, both ox parities (1024 MFMAs/wave), channel-split
// staging (26.3 KB LDS -> 4 blocks/CU). Coalesced epilogue. grid = B*32.
// ======================================================================
__global__ void __launch_bounds__(256, 4)
mdeconv1_k(const unsigned short* __restrict__ in, const unsigned short* __restrict__ wf,
           const float* __restrict__ bias, unsigned short* __restrict__ out)
{
    int blk = blockIdx.x;
    int bb = blk >> 5;
    int rem = blk & 31;
    int pp = rem >> 4;
    int i = rem & 15;
    int oy_a = pp + 4 * i;              // rows oy_a, oy_a+2
    int p = (oy_a + 1) & 1;
    int r0a = (oy_a + 1 - p) >> 1;
    int rbase = r0a - 1;
    int tid = threadIdx.x;
    int lane = tid & 63;
    int n0 = (tid >> 6) << 6;
    int m = lane & 15, quad = lane >> 4;
    __shared__ __align__(16) unsigned short win[3 * 34 * 132];   // 26.3 KB

    for (int par = 0; par < 2; ++par) {
        f32x4 acc[2][2][4];   // [row][mt][nt]
        f32x4 z = {0.f, 0.f, 0.f, 0.f};
        #pragma unroll
        for (int a = 0; a < 2; ++a)
            #pragma unroll
            for (int i2 = 0; i2 < 2; ++i2)
                #pragma unroll
                for (int t = 0; t < 4; ++t) acc[a][i2][t] = z;

        for (int c0 = 0; c0 < 256; c0 += 128) {
            __syncthreads();
            for (int s = tid; s < 3 * 34 * 16; s += 256) {
                int c16 = s & 15;
                int t2 = s >> 4;
                int col = t2 % 34;
                int rr = t2 / 34;
                int ih = rbase + rr, iw = col - 1;
                int4 v = make_int4(0, 0, 0, 0);
                if ((unsigned)ih < 32u && (unsigned)iw < 32u)
                    v = *(const int4*)&in[((((bb << 5) + ih) << 5) + iw) * 256 + c0 + (c16 << 3)];
                *(int4*)&win[(rr * 34 + col) * 132 + (c16 << 3)] = v;
            }
            __syncthreads();
            #pragma unroll
            for (int t = 0; t < 2; ++t) {
                int kh = p + 2 * t;
                #pragma unroll
                for (int u = 0; u < 2; ++u) {
                    int kw = (1 - par) + 2 * u;
                    int ixoff = par - u + 1;
                    #pragma unroll
                    for (int cch = 0; cch < 4; ++cch) {
                        const unsigned short* baA = &win[((1 - t) * 34 + m + ixoff) * 132 + (cch << 5) + (quad << 3)];
                        const unsigned short* baB = &win[((2 - t) * 34 + m + ixoff) * 132 + (cch << 5) + (quad << 3)];
                        bf16x8 a00 = *(const bf16x8*)baA;
                        bf16x8 a01 = *(const bf16x8*)(baA + 16 * 132);
                        bf16x8 a10 = *(const bf16x8*)baB;
                        bf16x8 a11 = *(const bf16x8*)(baB + 16 * 132);
                        int cg = (c0 >> 5) + cch;
                        int wbase = ((((kh << 2) + kw) * 8 + cg) * 256 + n0 + m) * 32 + (quad << 3);
                        bf16x8 b0 = *(const bf16x8*)&wf[wbase];
                        bf16x8 b1 = *(const bf16x8*)&wf[wbase + 16 * 32];
                        bf16x8 b2 = *(const bf16x8*)&wf[wbase + 32 * 32];
                        bf16x8 b3 = *(const bf16x8*)&wf[wbase + 48 * 32];
                        acc[0][0][0] = MFMA_B16(a00, b0, acc[0][0][0]);
                        acc[0][0][1] = MFMA_B16(a00, b1, acc[0][0][1]);
                        acc[0][0][2] = MFMA_B16(a00, b2, acc[0][0][2]);
                        acc[0][0][3] = MFMA_B16(a00, b3, acc[0][0][3]);
                        acc[0][1][0] = MFMA_B16(a01, b0, acc[0][1][0]);
                        acc[0][1][1] = MFMA_B16(a01, b1, acc[0][1][1]);
                        acc[0][1][2] = MFMA_B16(a01, b2, acc[0][1][2]);
                        acc[0][1][3] = MFMA_B16(a01, b3, acc[0][1][3]);
                        acc[1][0][0] = MFMA_B16(a10, b0, acc[1][0][0]);
                        acc[1][0][1] = MFMA_B16(a10, b1, acc[1][0][1]);
                        acc[1][0][2] = MFMA_B16(a10, b2, acc[1][0][2]);
                        acc[1][0][3] = MFMA_B16(a10, b3, acc[1][0][3]);
                        acc[1][1][0] = MFMA_B16(a11, b0, acc[1][1][0]);
                        acc[1][1][1] = MFMA_B16(a11, b1, acc[1][1][1]);
                        acc[1][1][2] = MFMA_B16(a11, b2, acc[1][1][2]);
                        acc[1][1][3] = MFMA_B16(a11, b3, acc[1][1][3]);
                    }
                }
            }
        }
        // coalesced epilogue: per oy row, stage 32 ox x 256 cols, then store
        #pragma unroll
        for (int row = 0; row < 2; ++row) {
            int oy = oy_a + 2 * row;
            __syncthreads();
            #pragma unroll
            for (int mt = 0; mt < 2; ++mt)
                #pragma unroll
                for (int nt = 0; nt < 4; ++nt) {
                    int col = n0 + nt * 16 + m;
                    float bs = bias[col];
                    #pragma unroll
                    for (int r = 0; r < 4; ++r) {
                        int oxi = mt * 16 + quad * 4 + r;
                        win[oxi * 264 + col] = f2b(fmaxf(acc[row][mt][nt][r] + bs, 0.f));
                    }
                }
            __syncthreads();
            int oxi2 = tid >> 3, seg = tid & 7;
            int gb = ((((bb << 6) + oy) << 6) + 2 * oxi2 + par) * 256 + seg * 32;
            #pragma unroll
            for (int u = 0; u < 4; ++u)
                *(int4*)&out[gb + u * 8] = *(int4*)&win[oxi2 * 264 + seg * 32 + u * 8];
        }
    }
}

// ======================================================================
// vqm: MFMA VQ + exact fp32 gather/loss. grid = B*32. (writes already
// 8B/lane contiguous -> no change)
// ======================================================================
__global__ void __launch_bounds__(256, 2)
vqm_k(const unsigned short* __restrict__ zeb, const float* __restrict__ zef,
      const unsigned short* __restrict__ embF, const float* __restrict__ embed,
      const float* __restrict__ nrm, unsigned short* __restrict__ zq,
      float* __restrict__ lacc)
{
    int bh = blockIdx.x;
    int tid = threadIdx.x;
    int lane = tid & 63;
    int wv = tid >> 6;
    int m = lane & 15, quad = lane >> 4;
    __shared__ __align__(16) unsigned short win[32 * 264];
    __shared__ float bvv[4][32];
    __shared__ int   bii[4][32];
    __shared__ int   bidx[32];
    int rowbase = bh << 13;
    for (int s = tid; s < 32 * 32; s += 256) {
        int c8 = s & 31, px = s >> 5;
        *(int4*)&win[px * 264 + (c8 << 3)] = *(const int4*)&zeb[rowbase + (px << 8) + (c8 << 3)];
    }
    __syncthreads();

    f32x4 acc[2][8];
    f32x4 z = {0.f, 0.f, 0.f, 0.f};
    #pragma unroll
    for (int i = 0; i < 2; ++i)
        #pragma unroll
        for (int j = 0; j < 8; ++j) acc[i][j] = z;

    #pragma unroll
    for (int cch = 0; cch < 8; ++cch) {
        bf16x8 a0 = *(const bf16x8*)&win[m * 264 + (cch << 5) + (quad << 3)];
        bf16x8 a1 = *(const bf16x8*)&win[(m + 16) * 264 + (cch << 5) + (quad << 3)];
        #pragma unroll
        for (int nt = 0; nt < 8; ++nt) {
            bf16x8 b = *(const bf16x8*)&embF[((cch << 9) + (wv << 7) + (nt << 4) + m) * 32 + (quad << 3)];
            acc[0][nt] = MFMA_B16(a0, b, acc[0][nt]);
            acc[1][nt] = MFMA_B16(a1, b, acc[1][nt]);
        }
    }

    float nv[8];
    #pragma unroll
    for (int nt = 0; nt < 8; ++nt) nv[nt] = nrm[(wv << 7) + (nt << 4) + m];

    #pragma unroll
    for (int mt = 0; mt < 2; ++mt)
        #pragma unroll
        for (int r = 0; r < 4; ++r) {
            float bv = 1e30f;
            int bi = 0x7fffffff;
            #pragma unroll
            for (int nt = 0; nt < 8; ++nt) {
                float d = nv[nt] - 2.f * acc[mt][nt][r];
                int n = (wv << 7) + (nt << 4) + m;
                if (d < bv || (d == bv && n < bi)) { bv = d; bi = n; }
            }
            #pragma unroll
            for (int off = 1; off < 16; off <<= 1) {
                float ov = __shfl_xor(bv, off);
                int oi = __shfl_xor(bi, off);
                if (ov < bv || (ov == bv && oi < bi)) { bv = ov; bi = oi; }
            }
            if (m == 0) {
                int px = mt * 16 + quad * 4 + r;
                bvv[wv][px] = bv;
                bii[wv][px] = bi;
            }
        }
    __syncthreads();
    if (tid < 32) {
        float bv = bvv[0][tid];
        int bi = bii[0][tid];
        #pragma unroll
        for (int w2 = 1; w2 < 4; ++w2) {
            float ov = bvv[w2][tid];
            int oi = bii[w2][tid];
            if (ov < bv || (ov == bv && oi < bi)) { bv = ov; bi = oi; }
        }
        bidx[tid] = bi;
    }
    __syncthreads();

    float lsum = 0.f;
    #pragma unroll
    for (int j = 0; j < 8; ++j) {
        int px = (wv << 3) + j;
        int bi = bidx[px];
        int pix = (bh << 5) + px;
        const float4 e = *(const float4*)&embed[bi * 256 + (lane << 2)];
        const float4 zv = *(const float4*)&zef[(pix << 8) + (lane << 2)];
        ushort4 eq;
        eq.x = f2b(e.x); eq.y = f2b(e.y); eq.z = f2b(e.z); eq.w = f2b(e.w);
        *(ushort4*)&zq[(pix << 8) + (lane << 2)] = eq;
        float dx = zv.x - e.x, dy = zv.y - e.y, dz = zv.z - e.z, dw = zv.w - e.w;
        lsum += dx * dx + dy * dy + dz * dz + dw * dw;
    }
    #pragma unroll
    for (int off = 1; off < 64; off <<= 1) lsum += __shfl_xor(lsum, off);
    if (lane == 0) atomicAdd(lacc, lsum);
}

// ======================================================================
// mdec2a: deconv2 pass 1 — Y[B*64*64, 48] = X[.,256] x Wg[256,48]
// (stores are full 64B sectors per 16-lane group -> no change)
// ======================================================================
__global__ void __launch_bounds__(256, 4)
mdec2a_k(const unsigned short* __restrict__ in, const unsigned short* __restrict__ wg,
         float* __restrict__ Y)
{
    int tid = threadIdx.x;
    int lane = tid & 63;
    int wv = tid >> 6;
    int m = lane & 15, quad = lane >> 4;
    __shared__ __align__(16) unsigned short win[64 * 264];
    int pxbase = blockIdx.x << 6;
    for (int s = tid; s < 64 * 32; s += 256) {
        int c8 = s & 31, px = s >> 5;
        *(int4*)&win[px * 264 + (c8 << 3)] = *(const int4*)&in[((pxbase + px) << 8) + (c8 << 3)];
    }
    __syncthreads();
    f32x4 acc[3];
    f32x4 z = {0.f, 0.f, 0.f, 0.f};
    acc[0] = z; acc[1] = z; acc[2] = z;
    #pragma unroll
    for (int cch = 0; cch < 8; ++cch) {
        bf16x8 a = *(const bf16x8*)&win[((wv << 4) + m) * 264 + (cch << 5) + (quad << 3)];
        #pragma unroll
        for (int nt = 0; nt < 3; ++nt) {
            bf16x8 b = *(const bf16x8*)&wg[(cch * 48 + nt * 16 + m) * 32 + (quad << 3)];
            acc[nt] = MFMA_B16(a, b, acc[nt]);
        }
    }
    #pragma unroll
    for (int nt = 0; nt < 3; ++nt)
        #pragma unroll
        for (int r = 0; r < 4; ++r) {
            int px = pxbase + (wv << 4) + quad * 4 + r;
            Y[px * 48 + nt * 16 + m] = acc[nt][r];
        }
}

// ======================================================================
// dec2b: deconv2 pass 2 — gather taps, +bias, sigmoid, NCHW out + losses.
// ======================================================================
__global__ void dec2b_k(const float* __restrict__ Y, const float* __restrict__ bias,
                        const float* __restrict__ lacc, float* __restrict__ out)
{
    if (blockIdx.x == 0 && threadIdx.x == 0) {
        float mloss = lacc[0] * (1.0f / 32768.0f);
        out[1572864] = mloss;
        out[1572865] = mloss;
    }
    int idx = blockIdx.x * 256 + threadIdx.x;
    int b = idx >> 14;
    int rem = idx & 16383;
    int oy = rem >> 7;
    int ox = rem & 127;
    int p = (oy + 1) & 1;
    int q = (ox + 1) & 1;
    float acc0 = bias[0], acc1 = bias[1], acc2 = bias[2];
    #pragma unroll
    for (int t = 0; t < 2; ++t) {
        int kh = p + 2 * t;
        int ih = (oy + 1 - kh) >> 1;
        if ((unsigned)ih >= 64u) continue;
        #pragma unroll
        for (int u = 0; u < 2; ++u) {
            int kw = q + 2 * u;
            int iw = (ox + 1 - kw) >> 1;
            if ((unsigned)iw >= 64u) continue;
            int base = ((((b << 6) + ih) << 6) + iw) * 48 + ((kh << 2) + kw) * 3;
            acc0 += Y[base];
            acc1 += Y[base + 1];
            acc2 += Y[base + 2];
        }
    }
    int obase = (b * 3 << 14) + (oy << 7) + ox;
    out[obase]           = 1.f / (1.f + expf(-acc0));
    out[obase + 16384]   = 1.f / (1.f + expf(-acc1));
    out[obase + 32768]   = 1.f / (1.f + expf(-acc2));
}

// ======================================================================
extern "C" void kernel_launch(void* const* d_in, const int* in_sizes, int n_in,
                              void* d_out, int out_size, void* d_ws, size_t ws_size,
                              hipStream_t stream)
{
    (void)in_sizes; (void)n_in; (void)out_size; (void)ws_size;
    const float* x      = (const float*)d_in[0];
    const float* embed  = (const float*)d_in[1];
    const float* e_w1   = (const float*)d_in[2];
    const float* e_w2   = (const float*)d_in[3];
    const float* e_r1a  = (const float*)d_in[4];
    const float* e_r1b  = (const float*)d_in[5];
    const float* e_r2a  = (const float*)d_in[6];
    const float* e_r2b  = (const float*)d_in[7];
    const float* d_r1a  = (const float*)d_in[8];
    const float* d_r1b  = (const float*)d_in[9];
    const float* d_r2a  = (const float*)d_in[10];
    const float* d_r2b  = (const float*)d_in[11];
    const float* dt1_w  = (const float*)d_in[12];
    const float* dt1_b  = (const float*)d_in[13];
    const float* dt2_w  = (const float*)d_in[14];
    const float* dt2_b  = (const float*)d_in[15];
    float* outp = (float*)d_out;

    // ---- workspace layout ----
    char* base = (char*)d_ws;
    size_t off = 0;
    auto alloc = [&](size_t bytes) { char* p = base + off; off += (bytes + 255) & ~size_t(255); return p; };
    unsigned short* A0b = (unsigned short*)alloc(67108864);  // (B,64,64,256) bf16
    float*          A1f = (float*)alloc(33554432);           // ze fp32; later Y
    unsigned short* L0  = (unsigned short*)alloc(16777216);
    unsigned short* L1  = (unsigned short*)alloc(16777216);
    unsigned short* Wf  = (unsigned short*)alloc(9437184);   // 10 frag-ordered weights
    unsigned short* Wg  = (unsigned short*)alloc(24576);     // deconv2 frag weights
    unsigned short* EmbF = (unsigned short*)alloc(262144);   // codebook frag bf16
    unsigned short* WgC = (unsigned short*)alloc(32768);     // conv1 frag weights
    float* Nrm  = (float*)alloc(2048);
    float* Lacc = (float*)alloc(64);
    float* Y = A1f;   // alias: ze dead after vqm_k

    unsigned short* Wf_ew2  = Wf;
    unsigned short* Wf_er1a = Wf + 1048576;
    unsigned short* Wf_er1b = Wf + 1638400;
    unsigned short* Wf_er2a = Wf + 1703936;
    unsigned short* Wf_er2b = Wf + 2293760;
    unsigned short* Wf_dr1a = Wf + 2359296;
    unsigned short* Wf_dr1b = Wf + 2949120;
    unsigned short* Wf_dr2a = Wf + 3014656;
    unsigned short* Wf_dr2b = Wf + 3604480;
    unsigned short* Wf_dt1  = Wf + 3670016;

    PermfArgs pa;
    const float* srcs[10] = {e_w2, e_r1a, e_r1b, e_r2a, e_r2b, d_r1a, d_r1b, d_r2a, d_r2b, dt1_w};
    int kws[10] = {4, 3, 1, 3, 1, 3, 1, 3, 1, 4};
    int sos[10] = {4096, 2304, 256, 2304, 256, 2304, 256, 2304, 256, 16};
    int sis[10] = {16, 9, 1, 9, 1, 9, 1, 9, 1, 4096};
    int shs[10] = {4, 3, 0, 3, 0, 3, 0, 3, 0, 4};
    int sws[10] = {1, 1, 0, 1, 0, 1, 0, 1, 0, 1};
    int cums[11] = {0, 1048576, 1638400, 1703936, 2293760, 2359296,
                    2949120, 3014656, 3604480, 3670016, 4718592};
    for (int k = 0; k < 10; ++k) {
        pa.src[k] = srcs[k]; pa.kw[k] = kws[k]; pa.so[k] = sos[k];
        pa.si[k] = sis[k]; pa.sh[k] = shs[k]; pa.sw[k] = sws[k];
        pa.cum[k] = cums[k];
    }
    pa.cum[10] = cums[10];

    prep_all_k<<<19185, 256, 0, stream>>>(pa, Wf, dt2_w, Wg, embed, EmbF, e_w1, WgC, Nrm, Lacc);

    // ---- encoder ----
    conv1m_k<<<32 * 64, 256, 0, stream>>>(x, WgC, A0b);
    mconv2_k<<<32 * 32, 256, 0, stream>>>(A0b, Wf_ew2, L1);                    // h
    mres_k<<<32 * 32, 256, 0, stream>>>(L1, Wf_er1a, Wf_er1b, L1, L0, nullptr, 0);   // r1 -> L0
    mres_k<<<32 * 32, 256, 0, stream>>>(L0, Wf_er2a, Wf_er2b, L0, L1, A1f, 1);       // ze -> L1 (bf16) + A1f (fp32)

    // ---- VQ ----
    vqm_k<<<32 * 32, 256, 0, stream>>>(L1, A1f, EmbF, embed, Nrm, L1, Lacc);   // zq -> L1

    // ---- decoder ----
    mres_k<<<32 * 32, 256, 0, stream>>>(L1, Wf_dr1a, Wf_dr1b, L1, L0, nullptr, 0);   // d1 -> L0
    mres_k<<<32 * 32, 256, 0, stream>>>(L0, Wf_dr2a, Wf_dr2b, L0, L1, nullptr, 0);   // d2 -> L1
    mdeconv1_k<<<32 * 32, 256, 0, stream>>>(L1, Wf_dt1, dt1_b, A0b);
    mdec2a_k<<<2048, 256, 0, stream>>>(A0b, Wg, Y);
    dec2b_k<<<2048, 256, 0, stream>>>(Y, dt2_b, Lacc, outp);
}